// Round 7
// baseline (6138.620 us; speedup 1.0000x reference)
//
#include <hip/hip_runtime.h>
#include <cmath>

#define Bn 64
#define Tn 512
#define Dn 400
#define Ln 25
#define Hn 200
#define G4n 800
#define TCn 64
#define NCH 8
#define NPADn 832
#define JW 40   // j per part-slice, ALL resident in VGPRs (per-SIMD pool = 2048, 4 waves -> 512/wave)

// ---- workspace layout (float offsets); total ~86 MB ----
constexpr size_t OFF_WIHT = 0;                                  // [2][400][832]
constexpr size_t OFF_WHHP = OFF_WIHT + (size_t)2*Dn*NPADn;      // [2][200(j)][200(k)][4(q)]
constexpr size_t OFF_BSUM = OFF_WHHP + (size_t)2*Hn*Hn*4;       // [2][800]
constexpr size_t OFF_G    = OFF_BSUM + (size_t)2*G4n;           // [2][64][64][800]
constexpr size_t OFF_HCAT = OFF_G + (size_t)2*Bn*TCn*G4n;       // [64][512][400]
constexpr size_t OFF_E    = OFF_HCAT + (size_t)Bn*Tn*2*Hn;      // [64][512][25]
constexpr size_t OFF_HST  = OFF_E + (size_t)Bn*Tn*Ln;           // [2][64][200]
constexpr size_t OFF_CST  = OFF_HST + (size_t)2*Bn*Hn;          // [2][64][200]
constexpr size_t OFF_PART = OFF_CST + (size_t)2*Bn*Hn;          // [64]

__device__ __forceinline__ float sigf(float x) { return 1.0f / (1.0f + expf(-x)); }

// ---------------- prep: transpose/pack weights, zero state ----------------
__global__ void prep_kernel(const float* __restrict__ Wih_f, const float* __restrict__ Whh_f,
                            const float* __restrict__ bih_f, const float* __restrict__ bhh_f,
                            const float* __restrict__ Wih_b, const float* __restrict__ Whh_b,
                            const float* __restrict__ bih_b, const float* __restrict__ bhh_b,
                            float* __restrict__ ws) {
    int tid = blockIdx.x * blockDim.x + threadIdx.x;
    int nth = gridDim.x * blockDim.x;
    float* WihT = ws + OFF_WIHT;
    float* WhhP = ws + OFF_WHHP;
    float* bsum = ws + OFF_BSUM;
    float* hst  = ws + OFF_HST;
    float* cst  = ws + OFF_CST;
    for (int i = tid; i < 2*Dn*NPADn; i += nth) {
        int d = i / (Dn*NPADn); int r = i % (Dn*NPADn); int k = r / NPADn; int g = r % NPADn;
        const float* W = d ? Wih_b : Wih_f;
        WihT[i] = (g < G4n) ? W[(size_t)g*Dn + k] : 0.0f;
    }
    for (int i = tid; i < 2*Hn*G4n; i += nth) {   // WhhP[d][j][k*4+q] = Whh[q*H+k][j]
        int d = i / (Hn*G4n); int r = i % (Hn*G4n);
        int j = r / G4n; int g = r % G4n;
        int k = g >> 2, q = g & 3;
        const float* W = d ? Whh_b : Whh_f;
        WhhP[i] = W[(size_t)(q*Hn + k)*Hn + j];
    }
    for (int i = tid; i < 2*G4n; i += nth) {
        int d = i / G4n; int g = i % G4n;
        bsum[i] = d ? (bih_b[g] + bhh_b[g]) : (bih_f[g] + bhh_f[g]);
    }
    for (int i = tid; i < 2*Bn*Hn; i += nth) { hst[i] = 0.0f; cst[i] = 0.0f; }
}

// ---------------- input projection GEMM for one time-chunk (both dirs) ----------------
// grid: (13 N-tiles, 32 b-pairs, 2 dir), 256 threads; BM=128 (2 b x 64 t), BN=64, BK=16
__global__ __launch_bounds__(256) void gemm_kernel(const float* __restrict__ X,
                                                   float* __restrict__ ws, int chunk) {
    const float* WihT = ws + OFF_WIHT;
    const float* bsum = ws + OFF_BSUM;
    float* G = ws + OFF_G;
    int d = blockIdx.z;
    int bp = blockIdx.y;          // batch pair
    int g0 = blockIdx.x * 64;
    int tid = threadIdx.x;
    int tx = tid % 16, ty = tid / 16;
    int t_base = (d == 0) ? chunk * TCn : (Tn - (chunk + 1) * TCn);
    const float* Bmat = WihT + (size_t)d * Dn * NPADn;

    __shared__ float As[16][136];
    __shared__ float Bs[16][68];
    float acc[8][4] = {{0.f}};
    int lr = tid / 2, lk = tid % 2;   // A load: row in [0,128), k-octet
    int bk = tid / 16, bg = tid % 16; // B load: k row, g-quad
    int a_b = bp * 2 + lr / 64;
    int a_t = t_base + (lr % 64);
    const float* Arow = X + ((size_t)a_b * Tn + a_t) * Dn;

    for (int kt = 0; kt < Dn; kt += 16) {
        float4 a4a = *(const float4*)(Arow + kt + lk * 8);
        float4 a4b = *(const float4*)(Arow + kt + lk * 8 + 4);
        float4 b4  = *(const float4*)(Bmat + (size_t)(kt + bk) * NPADn + g0 + bg * 4);
        __syncthreads();
        As[lk*8+0][lr] = a4a.x; As[lk*8+1][lr] = a4a.y;
        As[lk*8+2][lr] = a4a.z; As[lk*8+3][lr] = a4a.w;
        As[lk*8+4][lr] = a4b.x; As[lk*8+5][lr] = a4b.y;
        As[lk*8+6][lr] = a4b.z; As[lk*8+7][lr] = a4b.w;
        *(float4*)&Bs[bk][bg*4] = b4;
        __syncthreads();
        #pragma unroll
        for (int kk = 0; kk < 16; ++kk) {
            float4 af0 = *(const float4*)&As[kk][ty*8];
            float4 af1 = *(const float4*)&As[kk][ty*8+4];
            float4 bf  = *(const float4*)&Bs[kk][tx*4];
            acc[0][0] += af0.x*bf.x; acc[0][1] += af0.x*bf.y; acc[0][2] += af0.x*bf.z; acc[0][3] += af0.x*bf.w;
            acc[1][0] += af0.y*bf.x; acc[1][1] += af0.y*bf.y; acc[1][2] += af0.y*bf.z; acc[1][3] += af0.y*bf.w;
            acc[2][0] += af0.z*bf.x; acc[2][1] += af0.z*bf.y; acc[2][2] += af0.z*bf.z; acc[2][3] += af0.z*bf.w;
            acc[3][0] += af0.w*bf.x; acc[3][1] += af0.w*bf.y; acc[3][2] += af0.w*bf.z; acc[3][3] += af0.w*bf.w;
            acc[4][0] += af1.x*bf.x; acc[4][1] += af1.x*bf.y; acc[4][2] += af1.x*bf.z; acc[4][3] += af1.x*bf.w;
            acc[5][0] += af1.y*bf.x; acc[5][1] += af1.y*bf.y; acc[5][2] += af1.y*bf.z; acc[5][3] += af1.y*bf.w;
            acc[6][0] += af1.z*bf.x; acc[6][1] += af1.z*bf.y; acc[6][2] += af1.z*bf.z; acc[6][3] += af1.z*bf.w;
            acc[7][0] += af1.w*bf.x; acc[7][1] += af1.w*bf.y; acc[7][2] += af1.w*bf.z; acc[7][3] += af1.w*bf.w;
        }
    }
    #pragma unroll
    for (int ii = 0; ii < 8; ++ii) {
        int r = ty * 8 + ii;
        int b = bp * 2 + r / 64;
        int tloc = r % 64;
        #pragma unroll
        for (int jj = 0; jj < 4; ++jj) {
            int g = g0 + tx * 4 + jj;
            if (g < G4n) {
                int k = g % Hn, q = g / Hn;
                G[(((size_t)d*Bn + b)*TCn + tloc)*G4n + k*4 + q] = acc[ii][jj] + bsum[d*G4n + g];
            }
        }
    }
}

// ---------------- LSTM recurrence: Whh FULLY register-resident ----------------
// grid: (64 b, 2 dir) = 128 WGs, 1024 threads = 16 waves (4/SIMD -> up to 512 VGPR/wave).
// Phase A (tid<1000): part=tid/200, k=tid%200 -> gate-quad k over j-slice [part*40,+40),
//   all 40 weight-quads in VGPRs; 10 broadcast hbuf reads + 160 FMA + 1 partial write.
// Phase B (tid<800): u=(kk*4+qq); sums 5 partials, ONE activation per thread,
//   3 shfl_xor gather i,f,gg,o at qq==0 owner, who updates h,c and writes hbuf.
// Hcat store: deferred to next step, coalesced by threads 0..199.
__global__ __launch_bounds__(1024, 4) void rec_kernel(const float* __restrict__ mask,
                                                      float* __restrict__ ws, int chunk) {
    const float* G = ws + OFF_G;
    float* Hcat = ws + OFF_HCAT;
    float* hst = ws + OFF_HST;
    float* cst = ws + OFF_CST;
    const float* WP = ws + OFF_WHHP;

    int b = blockIdx.x;
    int d = blockIdx.y;
    int tid = threadIdx.x;
    int k = tid % 200;
    int part = tid / 200;          // 0..5 (part 5: 24 idle threads)
    bool act = (part < 5);
    int qq = tid & 3, kk = tid >> 2;
    bool bact = (tid < 800);

    __shared__ float4 partial[5][200];    // 15.6 KiB
    __shared__ float  hbuf[2][208];       // 1.6 KiB

    const float* Wd = WP + (size_t)d * Hn * G4n;
    int base = part * 40;
    float4 wreg[JW];
    if (act) {
        #pragma unroll
        for (int jj = 0; jj < JW; ++jj)
            wreg[jj] = *(const float4*)(Wd + (size_t)(base + jj) * G4n + k * 4);
    }
    size_t soff = ((size_t)d * Bn + b) * Hn;
    float hr = 0.f, cr = 0.f;
    if (bact && qq == 0) {
        hr = hst[soff + kk];
        cr = cst[soff + kk];
    }
    if (tid < 200) hbuf[0][tid] = hst[soff + tid];
    __syncthreads();

    const float* Grow = G + ((size_t)d * Bn + b) * TCn * G4n;
    const float* mrow = mask + (size_t)b * Tn;
    float* Hrow = Hcat + (size_t)b * Tn * (2 * Hn) + d * Hn;

    int cur = 0;
    for (int s = 0; s < TCn; ++s) {
        int tg, tloc;
        if (d == 0) { tloc = s; tg = chunk * TCn + s; }
        else        { tloc = TCn - 1 - s; tg = Tn - 1 - (chunk * TCn + s); }
        // ---- deferred coalesced Hcat store of previous step's h ----
        if (s > 0 && tid < 200) {
            int tgp = (d == 0) ? (chunk * TCn + s - 1) : (Tn - 1 - (chunk * TCn + s - 1));
            Hrow[(size_t)tgp * (2 * Hn) + tid] = hbuf[cur][tid];
        }
        // ---- B prefetch: 1 float gate-input per thread + mask ----
        float m_ = 0.f, gq = 0.f;
        if (bact) {
            m_ = mrow[tg];
            gq = Grow[(size_t)tloc * G4n + tid];
        }
        // ---- Phase A: gemv, all weights in registers ----
        if (act) {
            float4 acc = {0.f, 0.f, 0.f, 0.f};
            #pragma unroll
            for (int h4 = 0; h4 < 10; ++h4) {
                float4 hv = *(const float4*)&hbuf[cur][base + h4 * 4];
                acc.x += wreg[h4*4+0].x*hv.x; acc.y += wreg[h4*4+0].y*hv.x; acc.z += wreg[h4*4+0].z*hv.x; acc.w += wreg[h4*4+0].w*hv.x;
                acc.x += wreg[h4*4+1].x*hv.y; acc.y += wreg[h4*4+1].y*hv.y; acc.z += wreg[h4*4+1].z*hv.y; acc.w += wreg[h4*4+1].w*hv.y;
                acc.x += wreg[h4*4+2].x*hv.z; acc.y += wreg[h4*4+2].y*hv.z; acc.z += wreg[h4*4+2].z*hv.z; acc.w += wreg[h4*4+2].w*hv.z;
                acc.x += wreg[h4*4+3].x*hv.w; acc.y += wreg[h4*4+3].y*hv.w; acc.z += wreg[h4*4+3].z*hv.w; acc.w += wreg[h4*4+3].w*hv.w;
            }
            partial[part][k] = acc;
        }
        __syncthreads();
        // ---- Phase B: per-(k,q) reduce + activation, shuffle-gather at owner ----
        if (bact) {
            const float* pf = (const float*)partial;
            float g = gq + (((pf[0*800 + tid] + pf[1*800 + tid]) +
                             (pf[2*800 + tid] + pf[3*800 + tid])) + pf[4*800 + tid]);
            float arg = (qq == 2) ? 2.f * g : g;
            float sg = 1.f / (1.f + expf(-arg));
            float a = (qq == 2) ? 2.f * sg - 1.f : sg;   // tanh(g) = 2*sig(2g)-1
            float x1 = __shfl_xor(a, 1);
            float x2 = __shfl_xor(a, 2);
            float x3 = __shfl_xor(x1, 2);
            if (qq == 0) {
                float i_ = a, f_ = x1, gg_ = x2, o_ = x3;
                float cn = f_ * cr + i_ * gg_;
                float hn = o_ * tanhf(cn);
                cr = m_ * cn + (1.f - m_) * cr;
                hr = m_ * hn + (1.f - m_) * hr;
                hbuf[cur ^ 1][kk] = hr;
            }
        }
        __syncthreads();
        cur ^= 1;
    }
    // epilogue: last step's Hcat row + carry state
    if (tid < 200) {
        int tgp = (d == 0) ? (chunk * TCn + TCn - 1) : (Tn - 1 - (chunk * TCn + TCn - 1));
        Hrow[(size_t)tgp * (2 * Hn) + tid] = hbuf[cur][tid];
    }
    if (bact && qq == 0) {
        hst[soff + kk] = hr;
        cst[soff + kk] = cr;
    }
}

// ---------------- emissions: E = (Hcat @ Wl^T + bl) * mask ----------------
// grid: 256 WGs x 128 rows each
__global__ __launch_bounds__(256) void emis_kernel(const float* __restrict__ mask,
                                                   const float* __restrict__ Wl,
                                                   const float* __restrict__ bl,
                                                   float* __restrict__ ws) {
    const float* Hcat = ws + OFF_HCAT;
    float* E = ws + OFF_E;
    __shared__ float Wls[Ln * 404];
    __shared__ float Hs[16 * 404];
    int tid = threadIdx.x;
    for (int i = tid; i < Ln * 100; i += 256) {
        int l = i / 100, k4 = i % 100;
        *(float4*)&Wls[l*404 + k4*4] = *(const float4*)(Wl + (size_t)l*Dn + k4*4);
    }
    int rbase = blockIdx.x * 128;
    for (int sub = 0; sub < 8; ++sub) {
        int r0 = rbase + sub * 16;
        __syncthreads();
        for (int i = tid; i < 16 * 100; i += 256) {
            int r = i / 100, k4 = i % 100;
            *(float4*)&Hs[r*404 + k4*4] = *(const float4*)(Hcat + (size_t)(r0 + r)*Dn + k4*4);
        }
        __syncthreads();
        for (int o = tid; o < 16 * Ln; o += 256) {
            int r = o / Ln, l = o % Ln;
            float acc = 0.f;
            #pragma unroll 4
            for (int k4 = 0; k4 < 100; ++k4) {
                float4 h = *(const float4*)&Hs[r*404 + k4*4];
                float4 wv = *(const float4*)&Wls[l*404 + k4*4];
                acc += h.x*wv.x + h.y*wv.y + h.z*wv.z + h.w*wv.w;
            }
            int row = r0 + r;            // row == b*T + t
            float m = mask[row];
            E[(size_t)row * Ln + l] = (acc + bl[l]) * m;
        }
    }
}

// ---------------- fused CRF-forward + Viterbi: 128 one-wave blocks ----------------
__global__ __launch_bounds__(64) void decode_kernel(const float* __restrict__ mask,
                                                    const int* __restrict__ labels,
                                                    const float* __restrict__ trans,
                                                    const float* __restrict__ start,
                                                    const float* __restrict__ endv,
                                                    float* __restrict__ ws,
                                                    float* __restrict__ out) {
    int role = blockIdx.x >> 6;
    int b = blockIdx.x & 63;
    int l = threadIdx.x;
    const float* E = ws + OFF_E;
    float* part = ws + OFF_PART;

    __shared__ __align__(16) float Es[Tn * Ln];     // 51200 B
    __shared__ float trs[Ln * Ln];                  // 2500 B
    __shared__ __align__(16) float als[32];
    __shared__ unsigned char ptrs[Tn][Ln];          // 12800 B (vit only)
    __shared__ unsigned char ys[Tn];                // 512 B  (vit only)

    {   // stage E row, trans (single wave: ordering via lgkmcnt)
        const float4* src = (const float4*)(E + (size_t)b * Tn * Ln);
        float4* dst = (float4*)Es;
        for (int i = l; i < Tn * Ln / 4; i += 64) dst[i] = src[i];
        for (int i = l; i < Ln * Ln; i += 64) trs[i] = trans[i];
    }
    // sequence length (mask is 1s then 0s)
    float cnt = 0.f;
    for (int t = l; t < Tn; t += 64) cnt += mask[(size_t)b * Tn + t];
    for (int off = 32; off; off >>= 1) cnt += __shfl_xor(cnt, off);
    int len = (int)(cnt + 0.5f);

    // per-lane trans column: trc[j] = trans[j][l]; pads -1e30
    float trc[32];
    #pragma unroll
    for (int j = 0; j < 32; ++j) trc[j] = -1e30f;
    if (l < Ln) {
        for (int j = 0; j < Ln; ++j) trc[j] = trans[j * Ln + l];
    }
    __syncthreads();

    if (role == 0) {
        // ---- CRF forward ----
        float alpha = -1e30f;
        if (l < Ln) alpha = start[l] + Es[l];
        if (l < 32) als[l] = (l < Ln) ? alpha : -1e30f;
        for (int t = 1; t < len; ++t) {
            float av[32];
            {
                const float4* ap = (const float4*)als;
                #pragma unroll
                for (int q = 0; q < 8; ++q) {
                    float4 a = ap[q];
                    av[q*4+0] = a.x; av[q*4+1] = a.y; av[q*4+2] = a.z; av[q*4+3] = a.w;
                }
            }
            float v[32];
            #pragma unroll
            for (int j = 0; j < 32; ++j) v[j] = av[j] + trc[j];
            float r[16];
            #pragma unroll
            for (int j = 0; j < 16; ++j) r[j] = fmaxf(v[j], v[j+16]);
            #pragma unroll
            for (int j = 0; j < 8; ++j) r[j] = fmaxf(r[j], r[j+8]);
            #pragma unroll
            for (int j = 0; j < 4; ++j) r[j] = fmaxf(r[j], r[j+4]);
            float mx = fmaxf(fmaxf(r[0], r[1]), fmaxf(r[2], r[3]));
            float e[32];
            #pragma unroll
            for (int j = 0; j < 32; ++j) e[j] = __expf(v[j] - mx);
            #pragma unroll
            for (int j = 0; j < 16; ++j) e[j] += e[j+16];
            #pragma unroll
            for (int j = 0; j < 8; ++j) e[j] += e[j+8];
            #pragma unroll
            for (int j = 0; j < 4; ++j) e[j] += e[j+4];
            float s = (e[0] + e[1]) + (e[2] + e[3]);
            float nv = mx + __logf(s) + Es[t * Ln + l];
            if (l < Ln) { als[l] = nv; alpha = nv; }
        }
        // logZ
        float vfin = (l < Ln) ? alpha + endv[l] : -1e30f;
        float mxf = vfin;
        for (int off = 32; off; off >>= 1) mxf = fmaxf(mxf, __shfl_xor(mxf, off));
        float sf = (l < Ln) ? __expf(vfin - mxf) : 0.f;
        for (int off = 32; off; off >>= 1) sf += __shfl_xor(sf, off);
        float logZ = mxf + __logf(sf);
        // numerator
        float psum = 0.f;
        for (int t = l; t < len; t += 64) {
            if (t >= 1) {
                int lt = labels[(size_t)b * Tn + t];
                int lp = labels[(size_t)b * Tn + t - 1];
                psum += Es[t * Ln + lt] + trs[lp * Ln + lt];
            }
        }
        for (int off = 32; off; off >>= 1) psum += __shfl_xor(psum, off);
        if (l == 0) {
            int l0 = labels[(size_t)b * Tn];
            int yl = labels[(size_t)b * Tn + len - 1];
            part[b] = start[l0] + Es[l0] + psum + endv[yl] - logZ;
        }
    } else {
        // ---- Viterbi ----
        float delta = (l < Ln) ? start[l] + Es[l] : -1e30f;
        if (l < 32) als[l] = (l < Ln) ? delta : -1e30f;
        for (int t = 1; t < len; ++t) {
            float av[32];
            {
                const float4* ap = (const float4*)als;
                #pragma unroll
                for (int q = 0; q < 8; ++q) {
                    float4 a = ap[q];
                    av[q*4+0] = a.x; av[q*4+1] = a.y; av[q*4+2] = a.z; av[q*4+3] = a.w;
                }
            }
            float best = -1e30f; int ba = 0;
            #pragma unroll
            for (int j = 0; j < Ln; ++j) {
                float c = av[j] + trc[j];
                if (c > best) { best = c; ba = j; }   // strict >: first-max (jnp.argmax)
            }
            float nd = best + Es[t * Ln + l];
            if (l < Ln) { als[l] = nd; ptrs[t][l] = (unsigned char)ba; delta = nd; }
        }
        (void)delta;
        float av[32];
        {
            const float4* ap = (const float4*)als;
            #pragma unroll
            for (int q = 0; q < 8; ++q) {
                float4 a = ap[q];
                av[q*4+0] = a.x; av[q*4+1] = a.y; av[q*4+2] = a.z; av[q*4+3] = a.w;
            }
        }
        float bb = -1e30f; int y = 0;
        for (int j = 0; j < Ln; ++j) {
            float c = av[j] + endv[j];
            if (c > bb) { bb = c; y = j; }
        }
        if (l == 0) {
            ys[len - 1] = (unsigned char)y;
            int yy = y;
            for (int t = len - 1; t >= 1; --t) { yy = ptrs[t][yy]; ys[t - 1] = (unsigned char)yy; }
        }
        for (int t = l; t < Tn; t += 64) {
            out[1 + (size_t)b * Tn + t] = (t < len) ? (float)ys[t] : 0.f;
        }
    }
}

// ---------------- finalize loss ----------------
__global__ __launch_bounds__(64) void fin_kernel(float* __restrict__ ws, float* __restrict__ out) {
    const float* part = ws + OFF_PART;
    int l = threadIdx.x;
    float v = (l < Bn) ? part[l] : 0.f;
    for (int off = 32; off; off >>= 1) v += __shfl_xor(v, off);
    if (l == 0) out[0] = -v / (float)Bn;
}

extern "C" void kernel_launch(void* const* d_in, const int* in_sizes, int n_in,
                              void* d_out, int out_size, void* d_ws, size_t ws_size,
                              hipStream_t stream) {
    (void)in_sizes; (void)n_in; (void)out_size; (void)ws_size;
    const float* X      = (const float*)d_in[0];
    const float* mask   = (const float*)d_in[1];
    const int*   labels = (const int*)d_in[2];
    const float* Wih_f  = (const float*)d_in[3];
    const float* Whh_f  = (const float*)d_in[4];
    const float* bih_f  = (const float*)d_in[5];
    const float* bhh_f  = (const float*)d_in[6];
    const float* Wih_b  = (const float*)d_in[7];
    const float* Whh_b  = (const float*)d_in[8];
    const float* bih_b  = (const float*)d_in[9];
    const float* bhh_b  = (const float*)d_in[10];
    const float* Wl     = (const float*)d_in[11];
    const float* bl     = (const float*)d_in[12];
    const float* trans  = (const float*)d_in[13];
    const float* start  = (const float*)d_in[14];
    const float* endv   = (const float*)d_in[15];
    float* ws  = (float*)d_ws;
    float* out = (float*)d_out;

    prep_kernel<<<128, 256, 0, stream>>>(Wih_f, Whh_f, bih_f, bhh_f,
                                         Wih_b, Whh_b, bih_b, bhh_b, ws);
    for (int c = 0; c < NCH; ++c) {
        gemm_kernel<<<dim3(13, 32, 2), 256, 0, stream>>>(X, ws, c);
        rec_kernel<<<dim3(Bn, 2), 1024, 0, stream>>>(mask, ws, c);
    }
    emis_kernel<<<256, 256, 0, stream>>>(mask, Wl, bl, ws);
    decode_kernel<<<128, 64, 0, stream>>>(mask, labels, trans, start, endv, ws, out);
    fin_kernel<<<1, 64, 0, stream>>>(ws, out);
}

// Round 8
// 3037.456 us; speedup vs baseline: 2.0210x; 2.0210x over previous
//
#include <hip/hip_runtime.h>
#include <cmath>

#define Bn 64
#define Tn 512
#define Dn 400
#define Ln 25
#define Hn 200
#define G4n 800
#define TCn 64
#define NCH 8
#define NPADn 832
// Whh residency split per thread (40 j-quads total):
//  JV=20 in VGPRs (80 floats; wave cap ~128 VGPR at 16-wave WG), JL=8 in LDS, JS=12 streamed from L2.
#define JV 20
#define JL 8
#define JS 12

// ---- workspace layout (float offsets); total ~86 MB ----
constexpr size_t OFF_WIHT = 0;                                  // [2][400][832]
constexpr size_t OFF_WHHP = OFF_WIHT + (size_t)2*Dn*NPADn;      // [2][200(j)][200(k)][4(q)]
constexpr size_t OFF_BSUM = OFF_WHHP + (size_t)2*Hn*Hn*4;       // [2][800]
constexpr size_t OFF_G    = OFF_BSUM + (size_t)2*G4n;           // [2][64][64][800]
constexpr size_t OFF_HCAT = OFF_G + (size_t)2*Bn*TCn*G4n;       // [64][512][400]
constexpr size_t OFF_E    = OFF_HCAT + (size_t)Bn*Tn*2*Hn;      // [64][512][25]
constexpr size_t OFF_HST  = OFF_E + (size_t)Bn*Tn*Ln;           // [2][64][200]
constexpr size_t OFF_CST  = OFF_HST + (size_t)2*Bn*Hn;          // [2][64][200]
constexpr size_t OFF_PART = OFF_CST + (size_t)2*Bn*Hn;          // [64]

__device__ __forceinline__ float sigf(float x) { return 1.0f / (1.0f + expf(-x)); }

// ---------------- prep: transpose/pack weights, zero state ----------------
__global__ void prep_kernel(const float* __restrict__ Wih_f, const float* __restrict__ Whh_f,
                            const float* __restrict__ bih_f, const float* __restrict__ bhh_f,
                            const float* __restrict__ Wih_b, const float* __restrict__ Whh_b,
                            const float* __restrict__ bih_b, const float* __restrict__ bhh_b,
                            float* __restrict__ ws) {
    int tid = blockIdx.x * blockDim.x + threadIdx.x;
    int nth = gridDim.x * blockDim.x;
    float* WihT = ws + OFF_WIHT;
    float* WhhP = ws + OFF_WHHP;
    float* bsum = ws + OFF_BSUM;
    float* hst  = ws + OFF_HST;
    float* cst  = ws + OFF_CST;
    for (int i = tid; i < 2*Dn*NPADn; i += nth) {
        int d = i / (Dn*NPADn); int r = i % (Dn*NPADn); int k = r / NPADn; int g = r % NPADn;
        const float* W = d ? Wih_b : Wih_f;
        WihT[i] = (g < G4n) ? W[(size_t)g*Dn + k] : 0.0f;
    }
    for (int i = tid; i < 2*Hn*G4n; i += nth) {   // WhhP[d][j][k*4+q] = Whh[q*H+k][j]
        int d = i / (Hn*G4n); int r = i % (Hn*G4n);
        int j = r / G4n; int g = r % G4n;
        int k = g >> 2, q = g & 3;
        const float* W = d ? Whh_b : Whh_f;
        WhhP[i] = W[(size_t)(q*Hn + k)*Hn + j];
    }
    for (int i = tid; i < 2*G4n; i += nth) {
        int d = i / G4n; int g = i % G4n;
        bsum[i] = d ? (bih_b[g] + bhh_b[g]) : (bih_f[g] + bhh_f[g]);
    }
    for (int i = tid; i < 2*Bn*Hn; i += nth) { hst[i] = 0.0f; cst[i] = 0.0f; }
}

// ---------------- input projection GEMM for one time-chunk (both dirs) ----------------
// grid: (13 N-tiles, 32 b-pairs, 2 dir), 256 threads; BM=128 (2 b x 64 t), BN=64, BK=16
__global__ __launch_bounds__(256) void gemm_kernel(const float* __restrict__ X,
                                                   float* __restrict__ ws, int chunk) {
    const float* WihT = ws + OFF_WIHT;
    const float* bsum = ws + OFF_BSUM;
    float* G = ws + OFF_G;
    int d = blockIdx.z;
    int bp = blockIdx.y;          // batch pair
    int g0 = blockIdx.x * 64;
    int tid = threadIdx.x;
    int tx = tid % 16, ty = tid / 16;
    int t_base = (d == 0) ? chunk * TCn : (Tn - (chunk + 1) * TCn);
    const float* Bmat = WihT + (size_t)d * Dn * NPADn;

    __shared__ float As[16][136];
    __shared__ float Bs[16][68];
    float acc[8][4] = {{0.f}};
    int lr = tid / 2, lk = tid % 2;   // A load: row in [0,128), k-octet
    int bk = tid / 16, bg = tid % 16; // B load: k row, g-quad
    int a_b = bp * 2 + lr / 64;
    int a_t = t_base + (lr % 64);
    const float* Arow = X + ((size_t)a_b * Tn + a_t) * Dn;

    for (int kt = 0; kt < Dn; kt += 16) {
        float4 a4a = *(const float4*)(Arow + kt + lk * 8);
        float4 a4b = *(const float4*)(Arow + kt + lk * 8 + 4);
        float4 b4  = *(const float4*)(Bmat + (size_t)(kt + bk) * NPADn + g0 + bg * 4);
        __syncthreads();
        As[lk*8+0][lr] = a4a.x; As[lk*8+1][lr] = a4a.y;
        As[lk*8+2][lr] = a4a.z; As[lk*8+3][lr] = a4a.w;
        As[lk*8+4][lr] = a4b.x; As[lk*8+5][lr] = a4b.y;
        As[lk*8+6][lr] = a4b.z; As[lk*8+7][lr] = a4b.w;
        *(float4*)&Bs[bk][bg*4] = b4;
        __syncthreads();
        #pragma unroll
        for (int kk = 0; kk < 16; ++kk) {
            float4 af0 = *(const float4*)&As[kk][ty*8];
            float4 af1 = *(const float4*)&As[kk][ty*8+4];
            float4 bf  = *(const float4*)&Bs[kk][tx*4];
            acc[0][0] += af0.x*bf.x; acc[0][1] += af0.x*bf.y; acc[0][2] += af0.x*bf.z; acc[0][3] += af0.x*bf.w;
            acc[1][0] += af0.y*bf.x; acc[1][1] += af0.y*bf.y; acc[1][2] += af0.y*bf.z; acc[1][3] += af0.y*bf.w;
            acc[2][0] += af0.z*bf.x; acc[2][1] += af0.z*bf.y; acc[2][2] += af0.z*bf.z; acc[2][3] += af0.z*bf.w;
            acc[3][0] += af0.w*bf.x; acc[3][1] += af0.w*bf.y; acc[3][2] += af0.w*bf.z; acc[3][3] += af0.w*bf.w;
            acc[4][0] += af1.x*bf.x; acc[4][1] += af1.x*bf.y; acc[4][2] += af1.x*bf.z; acc[4][3] += af1.x*bf.w;
            acc[5][0] += af1.y*bf.x; acc[5][1] += af1.y*bf.y; acc[5][2] += af1.y*bf.z; acc[5][3] += af1.y*bf.w;
            acc[6][0] += af1.z*bf.x; acc[6][1] += af1.z*bf.y; acc[6][2] += af1.z*bf.z; acc[6][3] += af1.z*bf.w;
            acc[7][0] += af1.w*bf.x; acc[7][1] += af1.w*bf.y; acc[7][2] += af1.w*bf.z; acc[7][3] += af1.w*bf.w;
        }
    }
    #pragma unroll
    for (int ii = 0; ii < 8; ++ii) {
        int r = ty * 8 + ii;
        int b = bp * 2 + r / 64;
        int tloc = r % 64;
        #pragma unroll
        for (int jj = 0; jj < 4; ++jj) {
            int g = g0 + tx * 4 + jj;
            if (g < G4n) {
                int k = g % Hn, q = g / Hn;
                G[(((size_t)d*Bn + b)*TCn + tloc)*G4n + k*4 + q] = acc[ii][jj] + bsum[d*G4n + g];
            }
        }
    }
}

// ---------------- LSTM recurrence: 3-tier Whh residency (VGPR/LDS/L2-stream) ----------------
// grid: (64 b, 2 dir) = 128 WGs, 1024 threads = 16 waves (4/SIMD; VGPR cap ~128/wave).
// Phase A (tid<1000): part=tid/200, k=tid%200 -> gate-quad k over j-slice [part*40,+40):
//   j [0,20) in 20 NAMED float4 VGPR vars, [20,28) in LDS, [28,40) streamed from L2.
// Phase B (tid<800): u=(kk*4+qq); sums 5 partials, ONE activation per thread,
//   3 shfl_xor gather i,f,gg,o at qq==0 owner, who updates h,c and writes hbuf.
// Hcat store: deferred to next step, coalesced by threads 0..199.
__global__ __launch_bounds__(1024, 4) void rec_kernel(const float* __restrict__ mask,
                                                      float* __restrict__ ws, int chunk) {
    const float* G = ws + OFF_G;
    float* Hcat = ws + OFF_HCAT;
    float* hst = ws + OFF_HST;
    float* cst = ws + OFF_CST;
    const float* WP = ws + OFF_WHHP;

    int b = blockIdx.x;
    int d = blockIdx.y;
    int tid = threadIdx.x;
    int k = tid % 200;
    int part = tid / 200;          // 0..5 (part 5: 24 idle threads)
    bool act = (part < 5);
    int cbase = (act ? part : 0) * 40;   // clamped base so part-5 loads stay in-bounds
    int qq = tid & 3, kk = tid >> 2;
    bool bact = (tid < 800);

    __shared__ float4 wlds[JL][1000];     // 125 KiB   [jj][part*200+k]
    __shared__ float4 partial[5][200];    // 15.6 KiB
    __shared__ float  hbuf[2][208];       // 1.6 KiB

    const float* Wd = WP + (size_t)d * Hn * G4n;
    // ---- 20 weight quads in named VGPR vars (loaded unconditionally; RA-friendly) ----
    #define LW(i) float4 w##i = *(const float4*)(Wd + (size_t)(cbase + i) * G4n + k * 4);
    LW(0) LW(1) LW(2) LW(3) LW(4) LW(5) LW(6) LW(7) LW(8) LW(9)
    LW(10) LW(11) LW(12) LW(13) LW(14) LW(15) LW(16) LW(17) LW(18) LW(19)
    #undef LW
    if (act) {
        #pragma unroll
        for (int jj = 0; jj < JL; ++jj)
            wlds[jj][part * 200 + k] = *(const float4*)(Wd + (size_t)(cbase + JV + jj) * G4n + k * 4);
    }
    size_t soff = ((size_t)d * Bn + b) * Hn;
    float hr = 0.f, cr = 0.f;
    if (bact && qq == 0) {
        hr = hst[soff + kk];
        cr = cst[soff + kk];
    }
    if (tid < 200) hbuf[0][tid] = hst[soff + tid];
    __syncthreads();

    const float* Wst = Wd + (size_t)(cbase + JV + JL) * G4n + k * 4;
    const float* Grow = G + ((size_t)d * Bn + b) * TCn * G4n;
    const float* mrow = mask + (size_t)b * Tn;
    float* Hrow = Hcat + (size_t)b * Tn * (2 * Hn) + d * Hn;

    int cur = 0;
    for (int s = 0; s < TCn; ++s) {
        int tg, tloc;
        if (d == 0) { tloc = s; tg = chunk * TCn + s; }
        else        { tloc = TCn - 1 - s; tg = Tn - 1 - (chunk * TCn + s); }
        // ---- deferred coalesced Hcat store of previous step's h ----
        if (s > 0 && tid < 200) {
            int tgp = (d == 0) ? (chunk * TCn + s - 1) : (Tn - 1 - (chunk * TCn + s - 1));
            Hrow[(size_t)tgp * (2 * Hn) + tid] = hbuf[cur][tid];
        }
        // ---- B prefetch: 1 float gate-input per thread + mask ----
        float m_ = 0.f, gq = 0.f;
        if (bact) {
            m_ = mrow[tg];
            gq = Grow[(size_t)tloc * G4n + tid];
        }
        // ---- Phase A: streamed loads issued FIRST, then resident FMAs ----
        {
            float4 s0 = *(const float4*)(Wst + (size_t)0 * G4n);
            float4 s1 = *(const float4*)(Wst + (size_t)1 * G4n);
            float4 s2 = *(const float4*)(Wst + (size_t)2 * G4n);
            float4 s3 = *(const float4*)(Wst + (size_t)3 * G4n);
            float4 s4 = *(const float4*)(Wst + (size_t)4 * G4n);
            float4 s5 = *(const float4*)(Wst + (size_t)5 * G4n);
            float4 s6 = *(const float4*)(Wst + (size_t)6 * G4n);
            float4 s7 = *(const float4*)(Wst + (size_t)7 * G4n);
            float4 s8 = *(const float4*)(Wst + (size_t)8 * G4n);
            float4 s9 = *(const float4*)(Wst + (size_t)9 * G4n);
            float4 s10 = *(const float4*)(Wst + (size_t)10 * G4n);
            float4 s11 = *(const float4*)(Wst + (size_t)11 * G4n);
            float4 acc = {0.f, 0.f, 0.f, 0.f};
            #define FMA1(W, H) acc.x += (W).x*(H); acc.y += (W).y*(H); acc.z += (W).z*(H); acc.w += (W).w*(H);
            // VGPR tier: j = cbase+0 .. +19 (5 h-quads)
            {
                float4 hv;
                hv = *(const float4*)&hbuf[cur][cbase + 0];
                FMA1(w0, hv.x) FMA1(w1, hv.y) FMA1(w2, hv.z) FMA1(w3, hv.w)
                hv = *(const float4*)&hbuf[cur][cbase + 4];
                FMA1(w4, hv.x) FMA1(w5, hv.y) FMA1(w6, hv.z) FMA1(w7, hv.w)
                hv = *(const float4*)&hbuf[cur][cbase + 8];
                FMA1(w8, hv.x) FMA1(w9, hv.y) FMA1(w10, hv.z) FMA1(w11, hv.w)
                hv = *(const float4*)&hbuf[cur][cbase + 12];
                FMA1(w12, hv.x) FMA1(w13, hv.y) FMA1(w14, hv.z) FMA1(w15, hv.w)
                hv = *(const float4*)&hbuf[cur][cbase + 16];
                FMA1(w16, hv.x) FMA1(w17, hv.y) FMA1(w18, hv.z) FMA1(w19, hv.w)
            }
            // LDS tier: j = cbase+20 .. +27 (2 h-quads)
            {
                int lbase = part * 200 + k;   // valid only when act; guarded below
                if (act) {
                    float4 hv;
                    hv = *(const float4*)&hbuf[cur][cbase + JV];
                    FMA1(wlds[0][lbase], hv.x) FMA1(wlds[1][lbase], hv.y)
                    FMA1(wlds[2][lbase], hv.z) FMA1(wlds[3][lbase], hv.w)
                    hv = *(const float4*)&hbuf[cur][cbase + JV + 4];
                    FMA1(wlds[4][lbase], hv.x) FMA1(wlds[5][lbase], hv.y)
                    FMA1(wlds[6][lbase], hv.z) FMA1(wlds[7][lbase], hv.w)
                }
            }
            // streamed tier: j = cbase+28 .. +39 (3 h-quads)
            {
                float4 hv;
                hv = *(const float4*)&hbuf[cur][cbase + JV + JL];
                FMA1(s0, hv.x) FMA1(s1, hv.y) FMA1(s2, hv.z) FMA1(s3, hv.w)
                hv = *(const float4*)&hbuf[cur][cbase + JV + JL + 4];
                FMA1(s4, hv.x) FMA1(s5, hv.y) FMA1(s6, hv.z) FMA1(s7, hv.w)
                hv = *(const float4*)&hbuf[cur][cbase + JV + JL + 8];
                FMA1(s8, hv.x) FMA1(s9, hv.y) FMA1(s10, hv.z) FMA1(s11, hv.w)
            }
            #undef FMA1
            if (act) partial[part][k] = acc;
        }
        __syncthreads();
        // ---- Phase B: per-(k,q) reduce + activation, shuffle-gather at owner ----
        if (bact) {
            const float* pf = (const float*)partial;
            float g = gq + (((pf[0*800 + tid] + pf[1*800 + tid]) +
                             (pf[2*800 + tid] + pf[3*800 + tid])) + pf[4*800 + tid]);
            float arg = (qq == 2) ? 2.f * g : g;
            float sg = 1.f / (1.f + expf(-arg));
            float a = (qq == 2) ? 2.f * sg - 1.f : sg;   // tanh(g) = 2*sig(2g)-1
            float x1 = __shfl_xor(a, 1);
            float x2 = __shfl_xor(a, 2);
            float x3 = __shfl_xor(x1, 2);
            if (qq == 0) {
                float i_ = a, f_ = x1, gg_ = x2, o_ = x3;
                float cn = f_ * cr + i_ * gg_;
                float hn = o_ * tanhf(cn);
                cr = m_ * cn + (1.f - m_) * cr;
                hr = m_ * hn + (1.f - m_) * hr;
                hbuf[cur ^ 1][kk] = hr;
            }
        }
        __syncthreads();
        cur ^= 1;
    }
    // epilogue: last step's Hcat row + carry state
    if (tid < 200) {
        int tgp = (d == 0) ? (chunk * TCn + TCn - 1) : (Tn - 1 - (chunk * TCn + TCn - 1));
        Hrow[(size_t)tgp * (2 * Hn) + tid] = hbuf[cur][tid];
    }
    if (bact && qq == 0) {
        hst[soff + kk] = hr;
        cst[soff + kk] = cr;
    }
}

// ---------------- emissions: E = (Hcat @ Wl^T + bl) * mask ----------------
// grid: 256 WGs x 128 rows each
__global__ __launch_bounds__(256) void emis_kernel(const float* __restrict__ mask,
                                                   const float* __restrict__ Wl,
                                                   const float* __restrict__ bl,
                                                   float* __restrict__ ws) {
    const float* Hcat = ws + OFF_HCAT;
    float* E = ws + OFF_E;
    __shared__ float Wls[Ln * 404];
    __shared__ float Hs[16 * 404];
    int tid = threadIdx.x;
    for (int i = tid; i < Ln * 100; i += 256) {
        int l = i / 100, k4 = i % 100;
        *(float4*)&Wls[l*404 + k4*4] = *(const float4*)(Wl + (size_t)l*Dn + k4*4);
    }
    int rbase = blockIdx.x * 128;
    for (int sub = 0; sub < 8; ++sub) {
        int r0 = rbase + sub * 16;
        __syncthreads();
        for (int i = tid; i < 16 * 100; i += 256) {
            int r = i / 100, k4 = i % 100;
            *(float4*)&Hs[r*404 + k4*4] = *(const float4*)(Hcat + (size_t)(r0 + r)*Dn + k4*4);
        }
        __syncthreads();
        for (int o = tid; o < 16 * Ln; o += 256) {
            int r = o / Ln, l = o % Ln;
            float acc = 0.f;
            #pragma unroll 4
            for (int k4 = 0; k4 < 100; ++k4) {
                float4 h = *(const float4*)&Hs[r*404 + k4*4];
                float4 wv = *(const float4*)&Wls[l*404 + k4*4];
                acc += h.x*wv.x + h.y*wv.y + h.z*wv.z + h.w*wv.w;
            }
            int row = r0 + r;            // row == b*T + t
            float m = mask[row];
            E[(size_t)row * Ln + l] = (acc + bl[l]) * m;
        }
    }
}

// ---------------- fused CRF-forward + Viterbi: 128 one-wave blocks ----------------
__global__ __launch_bounds__(64) void decode_kernel(const float* __restrict__ mask,
                                                    const int* __restrict__ labels,
                                                    const float* __restrict__ trans,
                                                    const float* __restrict__ start,
                                                    const float* __restrict__ endv,
                                                    float* __restrict__ ws,
                                                    float* __restrict__ out) {
    int role = blockIdx.x >> 6;
    int b = blockIdx.x & 63;
    int l = threadIdx.x;
    const float* E = ws + OFF_E;
    float* part = ws + OFF_PART;

    __shared__ __align__(16) float Es[Tn * Ln];     // 51200 B
    __shared__ float trs[Ln * Ln];                  // 2500 B
    __shared__ __align__(16) float als[32];
    __shared__ unsigned char ptrs[Tn][Ln];          // 12800 B (vit only)
    __shared__ unsigned char ys[Tn];                // 512 B  (vit only)

    {   // stage E row, trans (single wave: ordering via lgkmcnt)
        const float4* src = (const float4*)(E + (size_t)b * Tn * Ln);
        float4* dst = (float4*)Es;
        for (int i = l; i < Tn * Ln / 4; i += 64) dst[i] = src[i];
        for (int i = l; i < Ln * Ln; i += 64) trs[i] = trans[i];
    }
    // sequence length (mask is 1s then 0s)
    float cnt = 0.f;
    for (int t = l; t < Tn; t += 64) cnt += mask[(size_t)b * Tn + t];
    for (int off = 32; off; off >>= 1) cnt += __shfl_xor(cnt, off);
    int len = (int)(cnt + 0.5f);

    // per-lane trans column: trc[j] = trans[j][l]; pads -1e30
    float trc[32];
    #pragma unroll
    for (int j = 0; j < 32; ++j) trc[j] = -1e30f;
    if (l < Ln) {
        for (int j = 0; j < Ln; ++j) trc[j] = trans[j * Ln + l];
    }
    __syncthreads();

    if (role == 0) {
        // ---- CRF forward ----
        float alpha = -1e30f;
        if (l < Ln) alpha = start[l] + Es[l];
        if (l < 32) als[l] = (l < Ln) ? alpha : -1e30f;
        for (int t = 1; t < len; ++t) {
            float av[32];
            {
                const float4* ap = (const float4*)als;
                #pragma unroll
                for (int q = 0; q < 8; ++q) {
                    float4 a = ap[q];
                    av[q*4+0] = a.x; av[q*4+1] = a.y; av[q*4+2] = a.z; av[q*4+3] = a.w;
                }
            }
            float v[32];
            #pragma unroll
            for (int j = 0; j < 32; ++j) v[j] = av[j] + trc[j];
            float r[16];
            #pragma unroll
            for (int j = 0; j < 16; ++j) r[j] = fmaxf(v[j], v[j+16]);
            #pragma unroll
            for (int j = 0; j < 8; ++j) r[j] = fmaxf(r[j], r[j+8]);
            #pragma unroll
            for (int j = 0; j < 4; ++j) r[j] = fmaxf(r[j], r[j+4]);
            float mx = fmaxf(fmaxf(r[0], r[1]), fmaxf(r[2], r[3]));
            float e[32];
            #pragma unroll
            for (int j = 0; j < 32; ++j) e[j] = __expf(v[j] - mx);
            #pragma unroll
            for (int j = 0; j < 16; ++j) e[j] += e[j+16];
            #pragma unroll
            for (int j = 0; j < 8; ++j) e[j] += e[j+8];
            #pragma unroll
            for (int j = 0; j < 4; ++j) e[j] += e[j+4];
            float s = (e[0] + e[1]) + (e[2] + e[3]);
            float nv = mx + __logf(s) + Es[t * Ln + l];
            if (l < Ln) { als[l] = nv; alpha = nv; }
        }
        // logZ
        float vfin = (l < Ln) ? alpha + endv[l] : -1e30f;
        float mxf = vfin;
        for (int off = 32; off; off >>= 1) mxf = fmaxf(mxf, __shfl_xor(mxf, off));
        float sf = (l < Ln) ? __expf(vfin - mxf) : 0.f;
        for (int off = 32; off; off >>= 1) sf += __shfl_xor(sf, off);
        float logZ = mxf + __logf(sf);
        // numerator
        float psum = 0.f;
        for (int t = l; t < len; t += 64) {
            if (t >= 1) {
                int lt = labels[(size_t)b * Tn + t];
                int lp = labels[(size_t)b * Tn + t - 1];
                psum += Es[t * Ln + lt] + trs[lp * Ln + lt];
            }
        }
        for (int off = 32; off; off >>= 1) psum += __shfl_xor(psum, off);
        if (l == 0) {
            int l0 = labels[(size_t)b * Tn];
            int yl = labels[(size_t)b * Tn + len - 1];
            part[b] = start[l0] + Es[l0] + psum + endv[yl] - logZ;
        }
    } else {
        // ---- Viterbi ----
        float delta = (l < Ln) ? start[l] + Es[l] : -1e30f;
        if (l < 32) als[l] = (l < Ln) ? delta : -1e30f;
        for (int t = 1; t < len; ++t) {
            float av[32];
            {
                const float4* ap = (const float4*)als;
                #pragma unroll
                for (int q = 0; q < 8; ++q) {
                    float4 a = ap[q];
                    av[q*4+0] = a.x; av[q*4+1] = a.y; av[q*4+2] = a.z; av[q*4+3] = a.w;
                }
            }
            float best = -1e30f; int ba = 0;
            #pragma unroll
            for (int j = 0; j < Ln; ++j) {
                float c = av[j] + trc[j];
                if (c > best) { best = c; ba = j; }   // strict >: first-max (jnp.argmax)
            }
            float nd = best + Es[t * Ln + l];
            if (l < Ln) { als[l] = nd; ptrs[t][l] = (unsigned char)ba; delta = nd; }
        }
        (void)delta;
        float av[32];
        {
            const float4* ap = (const float4*)als;
            #pragma unroll
            for (int q = 0; q < 8; ++q) {
                float4 a = ap[q];
                av[q*4+0] = a.x; av[q*4+1] = a.y; av[q*4+2] = a.z; av[q*4+3] = a.w;
            }
        }
        float bb = -1e30f; int y = 0;
        for (int j = 0; j < Ln; ++j) {
            float c = av[j] + endv[j];
            if (c > bb) { bb = c; y = j; }
        }
        if (l == 0) {
            ys[len - 1] = (unsigned char)y;
            int yy = y;
            for (int t = len - 1; t >= 1; --t) { yy = ptrs[t][yy]; ys[t - 1] = (unsigned char)yy; }
        }
        for (int t = l; t < Tn; t += 64) {
            out[1 + (size_t)b * Tn + t] = (t < len) ? (float)ys[t] : 0.f;
        }
    }
}

// ---------------- finalize loss ----------------
__global__ __launch_bounds__(64) void fin_kernel(float* __restrict__ ws, float* __restrict__ out) {
    const float* part = ws + OFF_PART;
    int l = threadIdx.x;
    float v = (l < Bn) ? part[l] : 0.f;
    for (int off = 32; off; off >>= 1) v += __shfl_xor(v, off);
    if (l == 0) out[0] = -v / (float)Bn;
}

extern "C" void kernel_launch(void* const* d_in, const int* in_sizes, int n_in,
                              void* d_out, int out_size, void* d_ws, size_t ws_size,
                              hipStream_t stream) {
    (void)in_sizes; (void)n_in; (void)out_size; (void)ws_size;
    const float* X      = (const float*)d_in[0];
    const float* mask   = (const float*)d_in[1];
    const int*   labels = (const int*)d_in[2];
    const float* Wih_f  = (const float*)d_in[3];
    const float* Whh_f  = (const float*)d_in[4];
    const float* bih_f  = (const float*)d_in[5];
    const float* bhh_f  = (const float*)d_in[6];
    const float* Wih_b  = (const float*)d_in[7];
    const float* Whh_b  = (const float*)d_in[8];
    const float* bih_b  = (const float*)d_in[9];
    const float* bhh_b  = (const float*)d_in[10];
    const float* Wl     = (const float*)d_in[11];
    const float* bl     = (const float*)d_in[12];
    const float* trans  = (const float*)d_in[13];
    const float* start  = (const float*)d_in[14];
    const float* endv   = (const float*)d_in[15];
    float* ws  = (float*)d_ws;
    float* out = (float*)d_out;

    prep_kernel<<<128, 256, 0, stream>>>(Wih_f, Whh_f, bih_f, bhh_f,
                                         Wih_b, Whh_b, bih_b, bhh_b, ws);
    for (int c = 0; c < NCH; ++c) {
        gemm_kernel<<<dim3(13, 32, 2), 256, 0, stream>>>(X, ws, c);
        rec_kernel<<<dim3(Bn, 2), 1024, 0, stream>>>(mask, ws, c);
    }
    emis_kernel<<<256, 256, 0, stream>>>(mask, Wl, bl, ws);
    decode_kernel<<<128, 64, 0, stream>>>(mask, labels, trans, start, endv, ws, out);
    fin_kernel<<<1, 64, 0, stream>>>(ws, out);
}

// Round 10
// 2986.673 us; speedup vs baseline: 2.0553x; 1.0170x over previous
//
#include <hip/hip_runtime.h>
#include <cmath>

#define Bn 64
#define Tn 512
#define Dn 400
#define Ln 25
#define Hn 200
#define G4n 800
#define TCn 64
#define NCH 8
#define NPADn 832
// Whh residency per thread (40 j-quads): 20 fp32 in VGPR, 12 bf16 in LDS, 8 bf16 streamed from L2.
#define JV 20
#define JLB 12
#define JSB 8

// ---- workspace layout (float offsets); total ~86.7 MB ----
constexpr size_t OFF_WIHT = 0;                                  // [2][400][832] f32
constexpr size_t OFF_WHHP = OFF_WIHT + (size_t)2*Dn*NPADn;      // [2][200(j)][800(g)] f32
constexpr size_t OFF_WHHB = OFF_WHHP + (size_t)2*Hn*G4n;        // [2][200(j)][800(g)] bf16 (ushort)
constexpr size_t OFF_BSUM = OFF_WHHB + (size_t)2*Hn*G4n/2;      // [2][800]
constexpr size_t OFF_G    = OFF_BSUM + (size_t)2*G4n;           // [2][64][64][800]
constexpr size_t OFF_HCAT = OFF_G + (size_t)2*Bn*TCn*G4n;       // [64][512][400]
constexpr size_t OFF_E    = OFF_HCAT + (size_t)Bn*Tn*2*Hn;      // [64][512][25]
constexpr size_t OFF_HST  = OFF_E + (size_t)Bn*Tn*Ln;           // [2][64][200]
constexpr size_t OFF_CST  = OFF_HST + (size_t)2*Bn*Hn;          // [2][64][200]
constexpr size_t OFF_PART = OFF_CST + (size_t)2*Bn*Hn;          // [64]

__device__ __forceinline__ float sigf(float x) { return 1.0f / (1.0f + expf(-x)); }
__device__ __forceinline__ float rdlane(float v, int j) {
    return __uint_as_float(__builtin_amdgcn_readlane(__float_as_uint(v), j));
}

// ---------------- prep: transpose/pack weights (fp32 + bf16), zero state ----------------
__global__ void prep_kernel(const float* __restrict__ Wih_f, const float* __restrict__ Whh_f,
                            const float* __restrict__ bih_f, const float* __restrict__ bhh_f,
                            const float* __restrict__ Wih_b, const float* __restrict__ Whh_b,
                            const float* __restrict__ bih_b, const float* __restrict__ bhh_b,
                            float* __restrict__ ws) {
    int tid = blockIdx.x * blockDim.x + threadIdx.x;
    int nth = gridDim.x * blockDim.x;
    float* WihT = ws + OFF_WIHT;
    float* WhhP = ws + OFF_WHHP;
    unsigned short* WhhB = (unsigned short*)(ws + OFF_WHHB);
    float* bsum = ws + OFF_BSUM;
    float* hst  = ws + OFF_HST;
    float* cst  = ws + OFF_CST;
    for (int i = tid; i < 2*Dn*NPADn; i += nth) {
        int d = i / (Dn*NPADn); int r = i % (Dn*NPADn); int k = r / NPADn; int g = r % NPADn;
        const float* W = d ? Wih_b : Wih_f;
        WihT[i] = (g < G4n) ? W[(size_t)g*Dn + k] : 0.0f;
    }
    for (int i = tid; i < 2*Hn*G4n; i += nth) {   // [d][j][k*4+q] = Whh[q*H+k][j]
        int d = i / (Hn*G4n); int r = i % (Hn*G4n);
        int j = r / G4n; int g = r % G4n;
        int k = g >> 2, q = g & 3;
        const float* W = d ? Whh_b : Whh_f;
        float v = W[(size_t)(q*Hn + k)*Hn + j];
        WhhP[i] = v;
        WhhB[i] = (unsigned short)(__float_as_uint(v) >> 16);   // bf16 truncate
    }
    for (int i = tid; i < 2*G4n; i += nth) {
        int d = i / G4n; int g = i % G4n;
        bsum[i] = d ? (bih_b[g] + bhh_b[g]) : (bih_f[g] + bhh_f[g]);
    }
    for (int i = tid; i < 2*Bn*Hn; i += nth) { hst[i] = 0.0f; cst[i] = 0.0f; }
}

// ---------------- input projection GEMM for one time-chunk (both dirs) ----------------
// grid: (13 N-tiles, 32 b-pairs, 2 dir), 256 threads; BM=128 (2 b x 64 t), BN=64, BK=16
__global__ __launch_bounds__(256) void gemm_kernel(const float* __restrict__ X,
                                                   float* __restrict__ ws, int chunk) {
    const float* WihT = ws + OFF_WIHT;
    const float* bsum = ws + OFF_BSUM;
    float* G = ws + OFF_G;
    int d = blockIdx.z;
    int bp = blockIdx.y;          // batch pair
    int g0 = blockIdx.x * 64;
    int tid = threadIdx.x;
    int tx = tid % 16, ty = tid / 16;
    int t_base = (d == 0) ? chunk * TCn : (Tn - (chunk + 1) * TCn);
    const float* Bmat = WihT + (size_t)d * Dn * NPADn;

    __shared__ float As[16][136];
    __shared__ float Bs[16][68];
    float acc[8][4] = {{0.f}};
    int lr = tid / 2, lk = tid % 2;   // A load: row in [0,128), k-octet
    int bk = tid / 16, bg = tid % 16; // B load: k row, g-quad
    int a_b = bp * 2 + lr / 64;
    int a_t = t_base + (lr % 64);
    const float* Arow = X + ((size_t)a_b * Tn + a_t) * Dn;

    for (int kt = 0; kt < Dn; kt += 16) {
        float4 a4a = *(const float4*)(Arow + kt + lk * 8);
        float4 a4b = *(const float4*)(Arow + kt + lk * 8 + 4);
        float4 b4  = *(const float4*)(Bmat + (size_t)(kt + bk) * NPADn + g0 + bg * 4);
        __syncthreads();
        As[lk*8+0][lr] = a4a.x; As[lk*8+1][lr] = a4a.y;
        As[lk*8+2][lr] = a4a.z; As[lk*8+3][lr] = a4a.w;
        As[lk*8+4][lr] = a4b.x; As[lk*8+5][lr] = a4b.y;
        As[lk*8+6][lr] = a4b.z; As[lk*8+7][lr] = a4b.w;
        *(float4*)&Bs[bk][bg*4] = b4;
        __syncthreads();
        #pragma unroll
        for (int kk = 0; kk < 16; ++kk) {
            float4 af0 = *(const float4*)&As[kk][ty*8];
            float4 af1 = *(const float4*)&As[kk][ty*8+4];
            float4 bf  = *(const float4*)&Bs[kk][tx*4];
            acc[0][0] += af0.x*bf.x; acc[0][1] += af0.x*bf.y; acc[0][2] += af0.x*bf.z; acc[0][3] += af0.x*bf.w;
            acc[1][0] += af0.y*bf.x; acc[1][1] += af0.y*bf.y; acc[1][2] += af0.y*bf.z; acc[1][3] += af0.y*bf.w;
            acc[2][0] += af0.z*bf.x; acc[2][1] += af0.z*bf.y; acc[2][2] += af0.z*bf.z; acc[2][3] += af0.z*bf.w;
            acc[3][0] += af0.w*bf.x; acc[3][1] += af0.w*bf.y; acc[3][2] += af0.w*bf.z; acc[3][3] += af0.w*bf.w;
            acc[4][0] += af1.x*bf.x; acc[4][1] += af1.x*bf.y; acc[4][2] += af1.x*bf.z; acc[4][3] += af1.x*bf.w;
            acc[5][0] += af1.y*bf.x; acc[5][1] += af1.y*bf.y; acc[5][2] += af1.y*bf.z; acc[5][3] += af1.y*bf.w;
            acc[6][0] += af1.z*bf.x; acc[6][1] += af1.z*bf.y; acc[6][2] += af1.z*bf.z; acc[6][3] += af1.z*bf.w;
            acc[7][0] += af1.w*bf.x; acc[7][1] += af1.w*bf.y; acc[7][2] += af1.w*bf.z; acc[7][3] += af1.w*bf.w;
        }
    }
    #pragma unroll
    for (int ii = 0; ii < 8; ++ii) {
        int r = ty * 8 + ii;
        int b = bp * 2 + r / 64;
        int tloc = r % 64;
        #pragma unroll
        for (int jj = 0; jj < 4; ++jj) {
            int g = g0 + tx * 4 + jj;
            if (g < G4n) {
                int k = g % Hn, q = g / Hn;
                G[(((size_t)d*Bn + b)*TCn + tloc)*G4n + k*4 + q] = acc[ii][jj] + bsum[d*G4n + g];
            }
        }
    }
}

// ---------------- LSTM recurrence: 3-tier Whh (fp32-VGPR / bf16-LDS / bf16-L2-stream) ----------------
// grid: (64 b, 2 dir) = 128 WGs, 1024 threads = 16 waves (4/SIMD; ~128 VGPR cap).
__global__ __launch_bounds__(1024, 4) void rec_kernel(const float* __restrict__ mask,
                                                      float* __restrict__ ws, int chunk) {
    const float* G = ws + OFF_G;
    float* Hcat = ws + OFF_HCAT;
    float* hst = ws + OFF_HST;
    float* cst = ws + OFF_CST;
    const float* WP = ws + OFF_WHHP;
    const unsigned short* WBbase = (const unsigned short*)(ws + OFF_WHHB);

    int b = blockIdx.x;
    int d = blockIdx.y;
    int tid = threadIdx.x;
    int k = tid % 200;
    int part = tid / 200;          // 0..5 (part 5: 24 idle threads)
    bool act = (part < 5);
    int cbase = (act ? part : 0) * 40;   // clamped so part-5 stays in-bounds
    int qq = tid & 3, kk = tid >> 2;
    bool bact = (tid < 800);

    __shared__ uint2  wldsB[JLB][1000];   // 96 KiB bf16 weight quads
    __shared__ float4 partial[5][200];    // 15.6 KiB
    __shared__ float  hbuf[2][208];       // 1.6 KiB

    const float* Wd = WP + (size_t)d * Hn * G4n;
    const unsigned short* WB = WBbase + (size_t)d * Hn * G4n;
    // ---- VGPR tier: 20 fp32 quads, named vars ----
    #define LW(i) float4 w##i = *(const float4*)(Wd + (size_t)(cbase + i) * G4n + k * 4);
    LW(0) LW(1) LW(2) LW(3) LW(4) LW(5) LW(6) LW(7) LW(8) LW(9)
    LW(10) LW(11) LW(12) LW(13) LW(14) LW(15) LW(16) LW(17) LW(18) LW(19)
    #undef LW
    // ---- LDS tier: stage 12 bf16 quads ----
    int lbase = (act ? part : 0) * 200 + k;
    if (act) {
        #pragma unroll
        for (int jj = 0; jj < JLB; ++jj)
            wldsB[jj][part * 200 + k] = *(const uint2*)(WB + (size_t)(cbase + JV + jj) * G4n + k * 4);
    }
    size_t soff = ((size_t)d * Bn + b) * Hn;
    float hr = 0.f, cr = 0.f;
    if (bact && qq == 0) {
        hr = hst[soff + kk];
        cr = cst[soff + kk];
    }
    if (tid < 200) hbuf[0][tid] = hst[soff + tid];
    __syncthreads();

    const unsigned short* WstB = WB + (size_t)(cbase + JV + JLB) * G4n + k * 4;
    const float* Grow = G + ((size_t)d * Bn + b) * TCn * G4n;
    const float* mrow = mask + (size_t)b * Tn;
    float* Hrow = Hcat + (size_t)b * Tn * (2 * Hn) + d * Hn;

    // bf16 quad (uint2) -> fma with scalar h
    #define FMAB(U, H) { \
        float bx = __uint_as_float((U).x << 16); \
        float by = __uint_as_float((U).x & 0xffff0000u); \
        float bz = __uint_as_float((U).y << 16); \
        float bw = __uint_as_float((U).y & 0xffff0000u); \
        acc.x += bx*(H); acc.y += by*(H); acc.z += bz*(H); acc.w += bw*(H); }
    #define FMA1(W, H) acc.x += (W).x*(H); acc.y += (W).y*(H); acc.z += (W).z*(H); acc.w += (W).w*(H);

    int cur = 0;
    for (int s = 0; s < TCn; ++s) {
        int tg, tloc;
        if (d == 0) { tloc = s; tg = chunk * TCn + s; }
        else        { tloc = TCn - 1 - s; tg = Tn - 1 - (chunk * TCn + s); }
        // ---- deferred coalesced Hcat store of previous step's h ----
        if (s > 0 && tid < 200) {
            int tgp = (d == 0) ? (chunk * TCn + s - 1) : (Tn - 1 - (chunk * TCn + s - 1));
            Hrow[(size_t)tgp * (2 * Hn) + tid] = hbuf[cur][tid];
        }
        // ---- phase-B prefetch: gate-input + mask ----
        float m_ = 0.f, gq = 0.f;
        if (bact) {
            m_ = mrow[tg];
            gq = Grow[(size_t)tloc * G4n + tid];
        }
        // ---- Phase A ----
        {
            // stream loads issued first (8 x 8B bf16 quads)
            uint2 t0 = *(const uint2*)(WstB + (size_t)0 * G4n);
            uint2 t1 = *(const uint2*)(WstB + (size_t)1 * G4n);
            uint2 t2 = *(const uint2*)(WstB + (size_t)2 * G4n);
            uint2 t3 = *(const uint2*)(WstB + (size_t)3 * G4n);
            uint2 t4 = *(const uint2*)(WstB + (size_t)4 * G4n);
            uint2 t5 = *(const uint2*)(WstB + (size_t)5 * G4n);
            uint2 t6 = *(const uint2*)(WstB + (size_t)6 * G4n);
            uint2 t7 = *(const uint2*)(WstB + (size_t)7 * G4n);
            float4 acc = {0.f, 0.f, 0.f, 0.f};
            float4 hv;
            // VGPR tier: j = cbase+0..19
            hv = *(const float4*)&hbuf[cur][cbase + 0];
            FMA1(w0, hv.x) FMA1(w1, hv.y) FMA1(w2, hv.z) FMA1(w3, hv.w)
            hv = *(const float4*)&hbuf[cur][cbase + 4];
            FMA1(w4, hv.x) FMA1(w5, hv.y) FMA1(w6, hv.z) FMA1(w7, hv.w)
            hv = *(const float4*)&hbuf[cur][cbase + 8];
            FMA1(w8, hv.x) FMA1(w9, hv.y) FMA1(w10, hv.z) FMA1(w11, hv.w)
            hv = *(const float4*)&hbuf[cur][cbase + 12];
            FMA1(w12, hv.x) FMA1(w13, hv.y) FMA1(w14, hv.z) FMA1(w15, hv.w)
            hv = *(const float4*)&hbuf[cur][cbase + 16];
            FMA1(w16, hv.x) FMA1(w17, hv.y) FMA1(w18, hv.z) FMA1(w19, hv.w)
            // LDS tier: j = cbase+20..31 (bf16)
            {
                uint2 u0 = wldsB[0][lbase], u1 = wldsB[1][lbase];
                uint2 u2 = wldsB[2][lbase], u3 = wldsB[3][lbase];
                hv = *(const float4*)&hbuf[cur][cbase + 20];
                FMAB(u0, hv.x) FMAB(u1, hv.y) FMAB(u2, hv.z) FMAB(u3, hv.w)
            }
            {
                uint2 u0 = wldsB[4][lbase], u1 = wldsB[5][lbase];
                uint2 u2 = wldsB[6][lbase], u3 = wldsB[7][lbase];
                hv = *(const float4*)&hbuf[cur][cbase + 24];
                FMAB(u0, hv.x) FMAB(u1, hv.y) FMAB(u2, hv.z) FMAB(u3, hv.w)
            }
            {
                uint2 u0 = wldsB[8][lbase], u1 = wldsB[9][lbase];
                uint2 u2 = wldsB[10][lbase], u3 = wldsB[11][lbase];
                hv = *(const float4*)&hbuf[cur][cbase + 28];
                FMAB(u0, hv.x) FMAB(u1, hv.y) FMAB(u2, hv.z) FMAB(u3, hv.w)
            }
            // stream tier: j = cbase+32..39 (bf16)
            hv = *(const float4*)&hbuf[cur][cbase + 32];
            FMAB(t0, hv.x) FMAB(t1, hv.y) FMAB(t2, hv.z) FMAB(t3, hv.w)
            hv = *(const float4*)&hbuf[cur][cbase + 36];
            FMAB(t4, hv.x) FMAB(t5, hv.y) FMAB(t6, hv.z) FMAB(t7, hv.w)
            if (act) partial[part][k] = acc;
        }
        __syncthreads();
        // ---- Phase B: per-(k,q) reduce + one activation, shuffle-gather at owner ----
        if (bact) {
            const float* pf = (const float*)partial;
            float g = gq + (((pf[0*800 + tid] + pf[1*800 + tid]) +
                             (pf[2*800 + tid] + pf[3*800 + tid])) + pf[4*800 + tid]);
            float arg = (qq == 2) ? 2.f * g : g;
            float sg = 1.f / (1.f + expf(-arg));
            float a = (qq == 2) ? 2.f * sg - 1.f : sg;   // tanh(g) = 2*sig(2g)-1
            float x1 = __shfl_xor(a, 1);
            float x2 = __shfl_xor(a, 2);
            float x3 = __shfl_xor(x1, 2);
            if (qq == 0) {
                float i_ = a, f_ = x1, gg_ = x2, o_ = x3;
                float cn = f_ * cr + i_ * gg_;
                float hn = o_ * tanhf(cn);
                cr = m_ * cn + (1.f - m_) * cr;
                hr = m_ * hn + (1.f - m_) * hr;
                hbuf[cur ^ 1][kk] = hr;
            }
        }
        __syncthreads();
        cur ^= 1;
    }
    #undef FMAB
    #undef FMA1
    // epilogue: last step's Hcat row + carry state
    if (tid < 200) {
        int tgp = (d == 0) ? (chunk * TCn + TCn - 1) : (Tn - 1 - (chunk * TCn + TCn - 1));
        Hrow[(size_t)tgp * (2 * Hn) + tid] = hbuf[cur][tid];
    }
    if (bact && qq == 0) {
        hst[soff + kk] = hr;
        cst[soff + kk] = cr;
    }
}

// ---------------- emissions: E = (Hcat @ Wl^T + bl) * mask ----------------
__global__ __launch_bounds__(256) void emis_kernel(const float* __restrict__ mask,
                                                   const float* __restrict__ Wl,
                                                   const float* __restrict__ bl,
                                                   float* __restrict__ ws) {
    const float* Hcat = ws + OFF_HCAT;
    float* E = ws + OFF_E;
    __shared__ float Wls[Ln * 404];
    __shared__ float Hs[16 * 404];
    int tid = threadIdx.x;
    for (int i = tid; i < Ln * 100; i += 256) {
        int l = i / 100, k4 = i % 100;
        *(float4*)&Wls[l*404 + k4*4] = *(const float4*)(Wl + (size_t)l*Dn + k4*4);
    }
    int rbase = blockIdx.x * 128;
    for (int sub = 0; sub < 8; ++sub) {
        int r0 = rbase + sub * 16;
        __syncthreads();
        for (int i = tid; i < 16 * 100; i += 256) {
            int r = i / 100, k4 = i % 100;
            *(float4*)&Hs[r*404 + k4*4] = *(const float4*)(Hcat + (size_t)(r0 + r)*Dn + k4*4);
        }
        __syncthreads();
        for (int o = tid; o < 16 * Ln; o += 256) {
            int r = o / Ln, l = o % Ln;
            float acc = 0.f;
            #pragma unroll 4
            for (int k4 = 0; k4 < 100; ++k4) {
                float4 h = *(const float4*)&Hs[r*404 + k4*4];
                float4 wv = *(const float4*)&Wls[l*404 + k4*4];
                acc += h.x*wv.x + h.y*wv.y + h.z*wv.z + h.w*wv.w;
            }
            int row = r0 + r;            // row == b*T + t
            float m = mask[row];
            E[(size_t)row * Ln + l] = (acc + bl[l]) * m;
        }
    }
}

// ---------------- fused CRF + Viterbi: 64 blocks x 128 threads (wave0=CRF, wave1=Viterbi) ----------------
// alpha/delta live in lane registers; broadcast via readlane (no LDS round-trip, no scan barriers).
__global__ __launch_bounds__(128) void decode_kernel(const float* __restrict__ mask,
                                                     const int* __restrict__ labels,
                                                     const float* __restrict__ trans,
                                                     const float* __restrict__ start,
                                                     const float* __restrict__ endv,
                                                     float* __restrict__ ws,
                                                     float* __restrict__ out) {
    int b = blockIdx.x;
    int tid = threadIdx.x;
    int wvid = tid >> 6;
    int l = tid & 63;
    const float* E = ws + OFF_E;
    float* part = ws + OFF_PART;

    __shared__ __align__(16) float Es[Tn * Ln];     // 51200 B
    __shared__ float trs[Ln * Ln];                  // 2500 B
    __shared__ unsigned char ptrs[Tn][Ln];          // 12800 B (vit)
    __shared__ unsigned char ys[Tn];                // 512 B  (vit)

    {   // cooperative staging (128 threads)
        const float4* src = (const float4*)(E + (size_t)b * Tn * Ln);
        float4* dst = (float4*)Es;
        for (int i = tid; i < Tn * Ln / 4; i += 128) dst[i] = src[i];
        for (int i = tid; i < Ln * Ln; i += 128) trs[i] = trans[i];
    }
    // per-wave: sequence length
    float cnt = 0.f;
    for (int t = l; t < Tn; t += 64) cnt += mask[(size_t)b * Tn + t];
    for (int off = 32; off; off >>= 1) cnt += __shfl_xor(cnt, off);
    int len = (int)(cnt + 0.5f);
    // per-lane trans column trc[j] = trans[j][l] (lanes >= Ln: -1e30 pads)
    float trc[Ln];
    #pragma unroll
    for (int j = 0; j < Ln; ++j) trc[j] = -1e30f;
    if (l < Ln) {
        #pragma unroll
        for (int j = 0; j < Ln; ++j) trc[j] = trans[j * Ln + l];
    }
    __syncthreads();

    if (wvid == 0) {
        // ---- CRF forward (register alpha, readlane broadcast) ----
        float alpha = (l < Ln) ? start[l] + Es[l] : -1e30f;
        for (int t = 1; t < len; ++t) {
            float v[Ln];
            #pragma unroll
            for (int j = 0; j < Ln; ++j) v[j] = rdlane(alpha, j) + trc[j];
            float r[12];
            #pragma unroll
            for (int j = 0; j < 12; ++j) r[j] = fmaxf(v[j], v[j + 12]);
            r[0] = fmaxf(r[0], v[24]);
            #pragma unroll
            for (int j = 0; j < 6; ++j) r[j] = fmaxf(r[j], r[j + 6]);
            #pragma unroll
            for (int j = 0; j < 3; ++j) r[j] = fmaxf(r[j], r[j + 3]);
            float mx = fmaxf(fmaxf(r[0], r[1]), r[2]);
            float e[Ln];
            #pragma unroll
            for (int j = 0; j < Ln; ++j) e[j] = __expf(v[j] - mx);
            #pragma unroll
            for (int j = 0; j < 12; ++j) e[j] += e[j + 12];
            e[0] += e[24];
            #pragma unroll
            for (int j = 0; j < 6; ++j) e[j] += e[j + 6];
            #pragma unroll
            for (int j = 0; j < 3; ++j) e[j] += e[j + 3];
            float s = (e[0] + e[1]) + e[2];
            float nv = mx + __logf(s) + Es[t * Ln + l];
            alpha = (l < Ln) ? nv : -1e30f;
        }
        float vfin = (l < Ln) ? alpha + endv[l] : -1e30f;
        float mxf = vfin;
        for (int off = 32; off; off >>= 1) mxf = fmaxf(mxf, __shfl_xor(mxf, off));
        float sf = (l < Ln) ? __expf(vfin - mxf) : 0.f;
        for (int off = 32; off; off >>= 1) sf += __shfl_xor(sf, off);
        float logZ = mxf + __logf(sf);
        float psum = 0.f;
        for (int t = l; t < len; t += 64) {
            if (t >= 1) {
                int lt = labels[(size_t)b * Tn + t];
                int lp = labels[(size_t)b * Tn + t - 1];
                psum += Es[t * Ln + lt] + trs[lp * Ln + lt];
            }
        }
        for (int off = 32; off; off >>= 1) psum += __shfl_xor(psum, off);
        if (l == 0) {
            int l0 = labels[(size_t)b * Tn];
            int yl = labels[(size_t)b * Tn + len - 1];
            part[b] = start[l0] + Es[l0] + psum + endv[yl] - logZ;
        }
    } else {
        // ---- Viterbi (register delta, readlane broadcast) ----
        float delta = (l < Ln) ? start[l] + Es[l] : -1e30f;
        for (int t = 1; t < len; ++t) {
            float best = -1e30f; int ba = 0;
            #pragma unroll
            for (int j = 0; j < Ln; ++j) {
                float c = rdlane(delta, j) + trc[j];
                if (c > best) { best = c; ba = j; }   // strict >: first-max (jnp.argmax)
            }
            float nd = best + Es[t * Ln + l];
            if (l < Ln) ptrs[t][l] = (unsigned char)ba;
            delta = (l < Ln) ? nd : -1e30f;
        }
        float bb = -1e30f; int y = 0;
        #pragma unroll
        for (int j = 0; j < Ln; ++j) {
            float c = rdlane(delta, j) + endv[j];
            if (c > bb) { bb = c; y = j; }
        }
        if (l == 0) {
            ys[len - 1] = (unsigned char)y;
            int yy = y;
            for (int t = len - 1; t >= 1; --t) { yy = ptrs[t][yy]; ys[t - 1] = (unsigned char)yy; }
        }
        for (int t = l; t < Tn; t += 64) {
            out[1 + (size_t)b * Tn + t] = (t < len) ? (float)ys[t] : 0.f;
        }
    }
}

// ---------------- finalize loss ----------------
__global__ __launch_bounds__(64) void fin_kernel(float* __restrict__ ws, float* __restrict__ out) {
    const float* part = ws + OFF_PART;
    int l = threadIdx.x;
    float v = (l < Bn) ? part[l] : 0.f;
    for (int off = 32; off; off >>= 1) v += __shfl_xor(v, off);
    if (l == 0) out[0] = -v / (float)Bn;
}

extern "C" void kernel_launch(void* const* d_in, const int* in_sizes, int n_in,
                              void* d_out, int out_size, void* d_ws, size_t ws_size,
                              hipStream_t stream) {
    (void)in_sizes; (void)n_in; (void)out_size; (void)ws_size;
    const float* X      = (const float*)d_in[0];
    const float* mask   = (const float*)d_in[1];
    const int*   labels = (const int*)d_in[2];
    const float* Wih_f  = (const float*)d_in[3];
    const float* Whh_f  = (const float*)d_in[4];
    const float* bih_f  = (const float*)d_in[5];
    const float* bhh_f  = (const float*)d_in[6];
    const float* Wih_b  = (const float*)d_in[7];
    const float* Whh_b  = (const float*)d_in[8];
    const float* bih_b  = (const float*)d_in[9];
    const float* bhh_b  = (const float*)d_in[10];
    const float* Wl     = (const float*)d_in[11];
    const float* bl     = (const float*)d_in[12];
    const float* trans  = (const float*)d_in[13];
    const float* start  = (const float*)d_in[14];
    const float* endv   = (const float*)d_in[15];
    float* ws  = (float*)d_ws;
    float* out = (float*)d_out;

    prep_kernel<<<128, 256, 0, stream>>>(Wih_f, Whh_f, bih_f, bhh_f,
                                         Wih_b, Whh_b, bih_b, bhh_b, ws);
    for (int c = 0; c < NCH; ++c) {
        gemm_kernel<<<dim3(13, 32, 2), 256, 0, stream>>>(X, ws, c);
        rec_kernel<<<dim3(Bn, 2), 1024, 0, stream>>>(mask, ws, c);
    }
    emis_kernel<<<256, 256, 0, stream>>>(mask, Wl, bl, ws);
    decode_kernel<<<64, 128, 0, stream>>>(mask, labels, trans, start, endv, ws, out);
    fin_kernel<<<1, 64, 0, stream>>>(ws, out);
}

// Round 11
// 2121.090 us; speedup vs baseline: 2.8941x; 1.4081x over previous
//
#include <hip/hip_runtime.h>
#include <cmath>

#define Bn 64
#define Tn 512
#define Dn 400
#define Ln 25
#define Hn 200
#define G4n 800
#define TCn 64
#define NCH 8
#define NPADn 832
// Whh residency per thread (40 j-quads): 20 fp32 in VGPR, 17 bf16 in LDS, 3 bf16 streamed (L1-resident).
#define JV 20
#define JLB 17
#define JSB 3

// ---- workspace layout (float offsets); total ~86.7 MB ----
constexpr size_t OFF_WIHT = 0;                                   // [2][400][832] f32
constexpr size_t OFF_WHHP = OFF_WIHT + (size_t)2*Dn*NPADn;       // [2][200(j)][800(g)] f32
constexpr size_t OFF_WHHB = OFF_WHHP + (size_t)2*Hn*G4n;         // [2][200][800] bf16
constexpr size_t OFF_BSUM = OFF_WHHB + (size_t)2*Hn*G4n/2;       // [2][800]
constexpr size_t OFF_GB   = OFF_BSUM + (size_t)2*G4n;            // 2 slots x [2][64][64][800] bf16
constexpr size_t OFF_HCAT = OFF_GB + (size_t)2*2*Bn*TCn*G4n/2;   // [64][512][400] f32
constexpr size_t OFF_E    = OFF_HCAT + (size_t)Bn*Tn*2*Hn;       // [64][512][25]
constexpr size_t OFF_HST  = OFF_E + (size_t)Bn*Tn*Ln;            // [2][64][200]
constexpr size_t OFF_CST  = OFF_HST + (size_t)2*Bn*Hn;           // [2][64][200]
constexpr size_t OFF_PART = OFF_CST + (size_t)2*Bn*Hn;           // [64]

#define SMEM_BYTES 153664   // rec: wldsB 136000 + partial 16000 + hbuf 1664; gemm: 4 x 13056 (union)

__device__ __forceinline__ float sigf(float x) { return 1.0f / (1.0f + expf(-x)); }
__device__ __forceinline__ float rdlane(float v, int j) {
    return __uint_as_float(__builtin_amdgcn_readlane(__float_as_uint(v), j));
}

// ---------------- prep: transpose/pack weights (fp32 + bf16), zero state ----------------
__global__ void prep_kernel(const float* __restrict__ Wih_f, const float* __restrict__ Whh_f,
                            const float* __restrict__ bih_f, const float* __restrict__ bhh_f,
                            const float* __restrict__ Wih_b, const float* __restrict__ Whh_b,
                            const float* __restrict__ bih_b, const float* __restrict__ bhh_b,
                            float* __restrict__ ws) {
    int tid = blockIdx.x * blockDim.x + threadIdx.x;
    int nth = gridDim.x * blockDim.x;
    float* WihT = ws + OFF_WIHT;
    float* WhhP = ws + OFF_WHHP;
    unsigned short* WhhB = (unsigned short*)(ws + OFF_WHHB);
    float* bsum = ws + OFF_BSUM;
    float* hst  = ws + OFF_HST;
    float* cst  = ws + OFF_CST;
    for (int i = tid; i < 2*Dn*NPADn; i += nth) {
        int d = i / (Dn*NPADn); int r = i % (Dn*NPADn); int k = r / NPADn; int g = r % NPADn;
        const float* W = d ? Wih_b : Wih_f;
        WihT[i] = (g < G4n) ? W[(size_t)g*Dn + k] : 0.0f;
    }
    for (int i = tid; i < 2*Hn*G4n; i += nth) {   // [d][j][k*4+q] = Whh[q*H+k][j]
        int d = i / (Hn*G4n); int r = i % (Hn*G4n);
        int j = r / G4n; int g = r % G4n;
        int k = g >> 2, q = g & 3;
        const float* W = d ? Whh_b : Whh_f;
        float v = W[(size_t)(q*Hn + k)*Hn + j];
        WhhP[i] = v;
        WhhB[i] = (unsigned short)(__float_as_uint(v) >> 16);   // bf16 truncate
    }
    for (int i = tid; i < 2*G4n; i += nth) {
        int d = i / G4n; int g = i % G4n;
        bsum[i] = d ? (bih_b[g] + bhh_b[g]) : (bih_f[g] + bhh_f[g]);
    }
    for (int i = tid; i < 2*Bn*Hn; i += nth) { hst[i] = 0.0f; cst[i] = 0.0f; }
}

// ---------------- gemm role: one 256-thread quarter computes one (g-tile, b-pair, dir) tile ----------------
__device__ __forceinline__ void gemm_role(const float* __restrict__ X, float* __restrict__ ws,
                                          int chunk, int tile, int tid, char* smem) {
    const float* WihT = ws + OFF_WIHT;
    const float* bsum = ws + OFF_BSUM;
    unsigned short* Gb = (unsigned short*)(ws + OFF_GB) + (size_t)(chunk & 1) * 2 * Bn * TCn * G4n;
    int q4 = tid >> 8;
    int t2 = tid & 255;
    float* As = (float*)(smem + q4 * 13056);        // [16][136]
    float* Bs = As + 16 * 136;                      // [16][68]
    int g0i = tile % 13; int rem = tile / 13;
    int bp = rem % 32;   int d = rem / 32;
    int g0 = g0i * 64;
    int tx = t2 % 16, ty = t2 / 16;
    int t_base = (d == 0) ? chunk * TCn : (Tn - (chunk + 1) * TCn);
    const float* Bmat = WihT + (size_t)d * Dn * NPADn;

    float acc[8][4] = {{0.f}};
    int lr = t2 / 2, lk = t2 % 2;
    int bk = t2 / 16, bg = t2 % 16;
    int a_b = bp * 2 + lr / 64;
    int a_t = t_base + (lr % 64);
    const float* Arow = X + ((size_t)a_b * Tn + a_t) * Dn;

    for (int kt = 0; kt < Dn; kt += 16) {
        float4 a4a = *(const float4*)(Arow + kt + lk * 8);
        float4 a4b = *(const float4*)(Arow + kt + lk * 8 + 4);
        float4 b4  = *(const float4*)(Bmat + (size_t)(kt + bk) * NPADn + g0 + bg * 4);
        __syncthreads();
        As[(lk*8+0)*136 + lr] = a4a.x; As[(lk*8+1)*136 + lr] = a4a.y;
        As[(lk*8+2)*136 + lr] = a4a.z; As[(lk*8+3)*136 + lr] = a4a.w;
        As[(lk*8+4)*136 + lr] = a4b.x; As[(lk*8+5)*136 + lr] = a4b.y;
        As[(lk*8+6)*136 + lr] = a4b.z; As[(lk*8+7)*136 + lr] = a4b.w;
        *(float4*)&Bs[bk*68 + bg*4] = b4;
        __syncthreads();
        #pragma unroll
        for (int kk = 0; kk < 16; ++kk) {
            float4 af0 = *(const float4*)&As[kk*136 + ty*8];
            float4 af1 = *(const float4*)&As[kk*136 + ty*8 + 4];
            float4 bf  = *(const float4*)&Bs[kk*68 + tx*4];
            acc[0][0] += af0.x*bf.x; acc[0][1] += af0.x*bf.y; acc[0][2] += af0.x*bf.z; acc[0][3] += af0.x*bf.w;
            acc[1][0] += af0.y*bf.x; acc[1][1] += af0.y*bf.y; acc[1][2] += af0.y*bf.z; acc[1][3] += af0.y*bf.w;
            acc[2][0] += af0.z*bf.x; acc[2][1] += af0.z*bf.y; acc[2][2] += af0.z*bf.z; acc[2][3] += af0.z*bf.w;
            acc[3][0] += af0.w*bf.x; acc[3][1] += af0.w*bf.y; acc[3][2] += af0.w*bf.z; acc[3][3] += af0.w*bf.w;
            acc[4][0] += af1.x*bf.x; acc[4][1] += af1.x*bf.y; acc[4][2] += af1.x*bf.z; acc[4][3] += af1.x*bf.w;
            acc[5][0] += af1.y*bf.x; acc[5][1] += af1.y*bf.y; acc[5][2] += af1.y*bf.z; acc[5][3] += af1.y*bf.w;
            acc[6][0] += af1.z*bf.x; acc[6][1] += af1.z*bf.y; acc[6][2] += af1.z*bf.z; acc[6][3] += af1.z*bf.w;
            acc[7][0] += af1.w*bf.x; acc[7][1] += af1.w*bf.y; acc[7][2] += af1.w*bf.z; acc[7][3] += af1.w*bf.w;
        }
    }
    #pragma unroll
    for (int ii = 0; ii < 8; ++ii) {
        int r = ty * 8 + ii;
        int b = bp * 2 + r / 64;
        int tloc = r % 64;
        #pragma unroll
        for (int jj = 0; jj < 4; ++jj) {
            int g = g0 + tx * 4 + jj;
            if (g < G4n) {
                int k = g % Hn, q = g / Hn;
                float v = acc[ii][jj] + bsum[d*G4n + g];
                Gb[(((size_t)d*Bn + b)*TCn + tloc)*G4n + k*4 + q] =
                    (unsigned short)(__float_as_uint(v) >> 16);
            }
        }
    }
}

// ---------------- rec role: 3-tier Whh (fp32-VGPR / bf16-LDS / bf16-L1-stream) ----------------
__device__ __forceinline__ void rec_role(const float* __restrict__ mask, float* __restrict__ ws,
                                         int chunk, int b, int d, int tid, char* smem) {
    const unsigned short* Gbs = (const unsigned short*)(ws + OFF_GB) + (size_t)(chunk & 1) * 2 * Bn * TCn * G4n;
    float* Hcat = ws + OFF_HCAT;
    float* hst = ws + OFF_HST;
    float* cst = ws + OFF_CST;
    const float* WP = ws + OFF_WHHP;
    const unsigned short* WBbase = (const unsigned short*)(ws + OFF_WHHB);

    uint2*  wldsB   = (uint2*)smem;                  // [JLB][1000]  136000 B
    float4* partial = (float4*)(smem + 136000);      // [5][200]     16000 B
    float*  hbuf    = (float*)(smem + 152000);       // [2][208]     1664 B

    int k = tid % 200;
    int part = tid / 200;          // 0..5 (part 5: 24 idle threads)
    bool act = (part < 5);
    int cbase = (act ? part : 0) * 40;
    int qq = tid & 3, kk = tid >> 2;
    bool bact = (tid < 800);

    const float* Wd = WP + (size_t)d * Hn * G4n;
    const unsigned short* WB = WBbase + (size_t)d * Hn * G4n;
    #define LW(i) float4 w##i = *(const float4*)(Wd + (size_t)(cbase + i) * G4n + k * 4);
    LW(0) LW(1) LW(2) LW(3) LW(4) LW(5) LW(6) LW(7) LW(8) LW(9)
    LW(10) LW(11) LW(12) LW(13) LW(14) LW(15) LW(16) LW(17) LW(18) LW(19)
    #undef LW
    int lbase = (act ? part : 0) * 200 + k;
    if (act) {
        #pragma unroll
        for (int jj = 0; jj < JLB; ++jj)
            wldsB[jj * 1000 + part * 200 + k] = *(const uint2*)(WB + (size_t)(cbase + JV + jj) * G4n + k * 4);
    }
    size_t soff = ((size_t)d * Bn + b) * Hn;
    float hr = 0.f, cr = 0.f;
    if (bact && qq == 0) {
        hr = hst[soff + kk];
        cr = cst[soff + kk];
    }
    if (tid < 200) hbuf[tid] = hst[soff + tid];
    __syncthreads();

    const unsigned short* WstB = WB + (size_t)(cbase + JV + JLB) * G4n + k * 4;
    const unsigned short* GbRow = Gbs + ((size_t)d * Bn + b) * TCn * G4n;
    const float* mrow = mask + (size_t)b * Tn;
    float* Hrow = Hcat + (size_t)b * Tn * (2 * Hn) + d * Hn;

    #define FMAB(U, H) { \
        float bx = __uint_as_float((U).x << 16); \
        float by = __uint_as_float((U).x & 0xffff0000u); \
        float bz = __uint_as_float((U).y << 16); \
        float bw = __uint_as_float((U).y & 0xffff0000u); \
        acc.x += bx*(H); acc.y += by*(H); acc.z += bz*(H); acc.w += bw*(H); }
    #define FMA1(W, H) acc.x += (W).x*(H); acc.y += (W).y*(H); acc.z += (W).z*(H); acc.w += (W).w*(H);

    int cur = 0;
    for (int s = 0; s < TCn; ++s) {
        int tg, tloc;
        if (d == 0) { tloc = s; tg = chunk * TCn + s; }
        else        { tloc = TCn - 1 - s; tg = Tn - 1 - (chunk * TCn + s); }
        // deferred coalesced Hcat store of previous step's h
        if (s > 0 && tid < 200) {
            int tgp = (d == 0) ? (chunk * TCn + s - 1) : (Tn - 1 - (chunk * TCn + s - 1));
            Hrow[(size_t)tgp * (2 * Hn) + tid] = hbuf[cur * 208 + tid];
        }
        // phase-B prefetch: gate-input (bf16) + mask
        float m_ = 0.f, gq = 0.f;
        if (bact) {
            m_ = mrow[tg];
            unsigned short gub = GbRow[(size_t)tloc * G4n + tid];
            gq = __uint_as_float((unsigned int)gub << 16);
        }
        // ---- Phase A ----
        {
            uint2 t0 = *(const uint2*)(WstB + (size_t)0 * G4n);
            uint2 t1 = *(const uint2*)(WstB + (size_t)1 * G4n);
            uint2 t2s = *(const uint2*)(WstB + (size_t)2 * G4n);
            float4 acc = {0.f, 0.f, 0.f, 0.f};
            float4 hv;
            const float* hb = hbuf + cur * 208;
            // VGPR tier: j = cbase+0..19
            hv = *(const float4*)&hb[cbase + 0];
            FMA1(w0, hv.x) FMA1(w1, hv.y) FMA1(w2, hv.z) FMA1(w3, hv.w)
            hv = *(const float4*)&hb[cbase + 4];
            FMA1(w4, hv.x) FMA1(w5, hv.y) FMA1(w6, hv.z) FMA1(w7, hv.w)
            hv = *(const float4*)&hb[cbase + 8];
            FMA1(w8, hv.x) FMA1(w9, hv.y) FMA1(w10, hv.z) FMA1(w11, hv.w)
            hv = *(const float4*)&hb[cbase + 12];
            FMA1(w12, hv.x) FMA1(w13, hv.y) FMA1(w14, hv.z) FMA1(w15, hv.w)
            hv = *(const float4*)&hb[cbase + 16];
            FMA1(w16, hv.x) FMA1(w17, hv.y) FMA1(w18, hv.z) FMA1(w19, hv.w)
            // LDS tier: j = cbase+20..35 (16 quads)
            {
                uint2 u0 = wldsB[0*1000+lbase], u1 = wldsB[1*1000+lbase];
                uint2 u2 = wldsB[2*1000+lbase], u3 = wldsB[3*1000+lbase];
                hv = *(const float4*)&hb[cbase + 20];
                FMAB(u0, hv.x) FMAB(u1, hv.y) FMAB(u2, hv.z) FMAB(u3, hv.w)
            }
            {
                uint2 u0 = wldsB[4*1000+lbase], u1 = wldsB[5*1000+lbase];
                uint2 u2 = wldsB[6*1000+lbase], u3 = wldsB[7*1000+lbase];
                hv = *(const float4*)&hb[cbase + 24];
                FMAB(u0, hv.x) FMAB(u1, hv.y) FMAB(u2, hv.z) FMAB(u3, hv.w)
            }
            {
                uint2 u0 = wldsB[8*1000+lbase], u1 = wldsB[9*1000+lbase];
                uint2 u2 = wldsB[10*1000+lbase], u3 = wldsB[11*1000+lbase];
                hv = *(const float4*)&hb[cbase + 28];
                FMAB(u0, hv.x) FMAB(u1, hv.y) FMAB(u2, hv.z) FMAB(u3, hv.w)
            }
            {
                uint2 u0 = wldsB[12*1000+lbase], u1 = wldsB[13*1000+lbase];
                uint2 u2 = wldsB[14*1000+lbase], u3 = wldsB[15*1000+lbase];
                hv = *(const float4*)&hb[cbase + 32];
                FMAB(u0, hv.x) FMAB(u1, hv.y) FMAB(u2, hv.z) FMAB(u3, hv.w)
            }
            // mixed quad: j = cbase+36 (LDS) + cbase+37..39 (stream, L1-resident)
            {
                uint2 u16 = wldsB[16*1000+lbase];
                hv = *(const float4*)&hb[cbase + 36];
                FMAB(u16, hv.x) FMAB(t0, hv.y) FMAB(t1, hv.z) FMAB(t2s, hv.w)
            }
            if (act) partial[part * 200 + k] = acc;
        }
        __syncthreads();
        // ---- Phase B ----
        if (bact) {
            const float* pf = (const float*)partial;
            float g = gq + (((pf[0*800 + tid] + pf[1*800 + tid]) +
                             (pf[2*800 + tid] + pf[3*800 + tid])) + pf[4*800 + tid]);
            float arg = (qq == 2) ? 2.f * g : g;
            float sg = 1.f / (1.f + expf(-arg));
            float a = (qq == 2) ? 2.f * sg - 1.f : sg;   // tanh(g) = 2*sig(2g)-1
            float x1 = __shfl_xor(a, 1);
            float x2 = __shfl_xor(a, 2);
            float x3 = __shfl_xor(x1, 2);
            if (qq == 0) {
                float i_ = a, f_ = x1, gg_ = x2, o_ = x3;
                float cn = f_ * cr + i_ * gg_;
                float hn = o_ * tanhf(cn);
                cr = m_ * cn + (1.f - m_) * cr;
                hr = m_ * hn + (1.f - m_) * hr;
                hbuf[(cur ^ 1) * 208 + kk] = hr;
            }
        }
        __syncthreads();
        cur ^= 1;
    }
    #undef FMAB
    #undef FMA1
    if (tid < 200) {
        int tgp = (d == 0) ? (chunk * TCn + TCn - 1) : (Tn - 1 - (chunk * TCn + TCn - 1));
        Hrow[(size_t)tgp * (2 * Hn) + tid] = hbuf[cur * 208 + tid];
    }
    if (bact && qq == 0) {
        hst[soff + kk] = hr;
        cst[soff + kk] = cr;
    }
}

// ---------------- fused launch: blocks [0,nrec) = rec(rec_chunk); rest = gemm(gemm_chunk) ----------------
__global__ __launch_bounds__(1024, 4) void fused_kernel(const float* __restrict__ X,
                                                        const float* __restrict__ mask,
                                                        float* __restrict__ ws,
                                                        int rec_chunk, int gemm_chunk, int nrec) {
    __shared__ __align__(16) char smem[SMEM_BYTES];
    int bx = blockIdx.x;
    int tid = threadIdx.x;
    if (bx < nrec) {
        rec_role(mask, ws, rec_chunk, bx & 63, bx >> 6, tid, smem);
    } else {
        int tile = (bx - nrec) * 4 + (tid >> 8);
        gemm_role(X, ws, gemm_chunk, tile, tid, smem);
    }
}

// ---------------- emissions: E = (Hcat @ Wl^T + bl) * mask ----------------
__global__ __launch_bounds__(256) void emis_kernel(const float* __restrict__ mask,
                                                   const float* __restrict__ Wl,
                                                   const float* __restrict__ bl,
                                                   float* __restrict__ ws) {
    const float* Hcat = ws + OFF_HCAT;
    float* E = ws + OFF_E;
    __shared__ float Wls[Ln * 404];
    __shared__ float Hs[16 * 404];
    int tid = threadIdx.x;
    for (int i = tid; i < Ln * 100; i += 256) {
        int l = i / 100, k4 = i % 100;
        *(float4*)&Wls[l*404 + k4*4] = *(const float4*)(Wl + (size_t)l*Dn + k4*4);
    }
    int rbase = blockIdx.x * 128;
    for (int sub = 0; sub < 8; ++sub) {
        int r0 = rbase + sub * 16;
        __syncthreads();
        for (int i = tid; i < 16 * 100; i += 256) {
            int r = i / 100, k4 = i % 100;
            *(float4*)&Hs[r*404 + k4*4] = *(const float4*)(Hcat + (size_t)(r0 + r)*Dn + k4*4);
        }
        __syncthreads();
        for (int o = tid; o < 16 * Ln; o += 256) {
            int r = o / Ln, l = o % Ln;
            float acc = 0.f;
            #pragma unroll 4
            for (int k4 = 0; k4 < 100; ++k4) {
                float4 h = *(const float4*)&Hs[r*404 + k4*4];
                float4 wv = *(const float4*)&Wls[l*404 + k4*4];
                acc += h.x*wv.x + h.y*wv.y + h.z*wv.z + h.w*wv.w;
            }
            int row = r0 + r;            // row == b*T + t
            float m = mask[row];
            E[(size_t)row * Ln + l] = (acc + bl[l]) * m;
        }
    }
}

// ---------------- fused CRF + Viterbi: 64 blocks x 128 threads (wave0=CRF, wave1=Viterbi) ----------------
__global__ __launch_bounds__(128) void decode_kernel(const float* __restrict__ mask,
                                                     const int* __restrict__ labels,
                                                     const float* __restrict__ trans,
                                                     const float* __restrict__ start,
                                                     const float* __restrict__ endv,
                                                     float* __restrict__ ws,
                                                     float* __restrict__ out) {
    int b = blockIdx.x;
    int tid = threadIdx.x;
    int wvid = tid >> 6;
    int l = tid & 63;
    const float* E = ws + OFF_E;
    float* part = ws + OFF_PART;

    __shared__ __align__(16) float Es[Tn * Ln];
    __shared__ float trs[Ln * Ln];
    __shared__ unsigned char ptrs[Tn][Ln];
    __shared__ unsigned char ys[Tn];

    {
        const float4* src = (const float4*)(E + (size_t)b * Tn * Ln);
        float4* dst = (float4*)Es;
        for (int i = tid; i < Tn * Ln / 4; i += 128) dst[i] = src[i];
        for (int i = tid; i < Ln * Ln; i += 128) trs[i] = trans[i];
    }
    float cnt = 0.f;
    for (int t = l; t < Tn; t += 64) cnt += mask[(size_t)b * Tn + t];
    for (int off = 32; off; off >>= 1) cnt += __shfl_xor(cnt, off);
    int len = (int)(cnt + 0.5f);
    float trc[Ln];
    #pragma unroll
    for (int j = 0; j < Ln; ++j) trc[j] = -1e30f;
    if (l < Ln) {
        #pragma unroll
        for (int j = 0; j < Ln; ++j) trc[j] = trans[j * Ln + l];
    }
    __syncthreads();

    if (wvid == 0) {
        float alpha = (l < Ln) ? start[l] + Es[l] : -1e30f;
        for (int t = 1; t < len; ++t) {
            float v[Ln];
            #pragma unroll
            for (int j = 0; j < Ln; ++j) v[j] = rdlane(alpha, j) + trc[j];
            float r[12];
            #pragma unroll
            for (int j = 0; j < 12; ++j) r[j] = fmaxf(v[j], v[j + 12]);
            r[0] = fmaxf(r[0], v[24]);
            #pragma unroll
            for (int j = 0; j < 6; ++j) r[j] = fmaxf(r[j], r[j + 6]);
            #pragma unroll
            for (int j = 0; j < 3; ++j) r[j] = fmaxf(r[j], r[j + 3]);
            float mx = fmaxf(fmaxf(r[0], r[1]), r[2]);
            float e[Ln];
            #pragma unroll
            for (int j = 0; j < Ln; ++j) e[j] = __expf(v[j] - mx);
            #pragma unroll
            for (int j = 0; j < 12; ++j) e[j] += e[j + 12];
            e[0] += e[24];
            #pragma unroll
            for (int j = 0; j < 6; ++j) e[j] += e[j + 6];
            #pragma unroll
            for (int j = 0; j < 3; ++j) e[j] += e[j + 3];
            float s = (e[0] + e[1]) + e[2];
            float nv = mx + __logf(s) + Es[t * Ln + l];
            alpha = (l < Ln) ? nv : -1e30f;
        }
        float vfin = (l < Ln) ? alpha + endv[l] : -1e30f;
        float mxf = vfin;
        for (int off = 32; off; off >>= 1) mxf = fmaxf(mxf, __shfl_xor(mxf, off));
        float sf = (l < Ln) ? __expf(vfin - mxf) : 0.f;
        for (int off = 32; off; off >>= 1) sf += __shfl_xor(sf, off);
        float logZ = mxf + __logf(sf);
        float psum = 0.f;
        for (int t = l; t < len; t += 64) {
            if (t >= 1) {
                int lt = labels[(size_t)b * Tn + t];
                int lp = labels[(size_t)b * Tn + t - 1];
                psum += Es[t * Ln + lt] + trs[lp * Ln + lt];
            }
        }
        for (int off = 32; off; off >>= 1) psum += __shfl_xor(psum, off);
        if (l == 0) {
            int l0 = labels[(size_t)b * Tn];
            int yl = labels[(size_t)b * Tn + len - 1];
            part[b] = start[l0] + Es[l0] + psum + endv[yl] - logZ;
        }
    } else {
        float delta = (l < Ln) ? start[l] + Es[l] : -1e30f;
        for (int t = 1; t < len; ++t) {
            float best = -1e30f; int ba = 0;
            #pragma unroll
            for (int j = 0; j < Ln; ++j) {
                float c = rdlane(delta, j) + trc[j];
                if (c > best) { best = c; ba = j; }   // strict >: first-max (jnp.argmax)
            }
            float nd = best + Es[t * Ln + l];
            if (l < Ln) ptrs[t][l] = (unsigned char)ba;
            delta = (l < Ln) ? nd : -1e30f;
        }
        float bb = -1e30f; int y = 0;
        #pragma unroll
        for (int j = 0; j < Ln; ++j) {
            float c = rdlane(delta, j) + endv[j];
            if (c > bb) { bb = c; y = j; }
        }
        if (l == 0) {
            ys[len - 1] = (unsigned char)y;
            int yy = y;
            for (int t = len - 1; t >= 1; --t) { yy = ptrs[t][yy]; ys[t - 1] = (unsigned char)yy; }
        }
        for (int t = l; t < Tn; t += 64) {
            out[1 + (size_t)b * Tn + t] = (t < len) ? (float)ys[t] : 0.f;
        }
    }
}

// ---------------- finalize loss ----------------
__global__ __launch_bounds__(64) void fin_kernel(float* __restrict__ ws, float* __restrict__ out) {
    const float* part = ws + OFF_PART;
    int l = threadIdx.x;
    float v = (l < Bn) ? part[l] : 0.f;
    for (int off = 32; off; off >>= 1) v += __shfl_xor(v, off);
    if (l == 0) out[0] = -v / (float)Bn;
}

extern "C" void kernel_launch(void* const* d_in, const int* in_sizes, int n_in,
                              void* d_out, int out_size, void* d_ws, size_t ws_size,
                              hipStream_t stream) {
    (void)in_sizes; (void)n_in; (void)out_size; (void)ws_size;
    const float* X      = (const float*)d_in[0];
    const float* mask   = (const float*)d_in[1];
    const int*   labels = (const int*)d_in[2];
    const float* Wih_f  = (const float*)d_in[3];
    const float* Whh_f  = (const float*)d_in[4];
    const float* bih_f  = (const float*)d_in[5];
    const float* bhh_f  = (const float*)d_in[6];
    const float* Wih_b  = (const float*)d_in[7];
    const float* Whh_b  = (const float*)d_in[8];
    const float* bih_b  = (const float*)d_in[9];
    const float* bhh_b  = (const float*)d_in[10];
    const float* Wl     = (const float*)d_in[11];
    const float* bl     = (const float*)d_in[12];
    const float* trans  = (const float*)d_in[13];
    const float* start  = (const float*)d_in[14];
    const float* endv   = (const float*)d_in[15];
    float* ws  = (float*)d_ws;
    float* out = (float*)d_out;

    prep_kernel<<<128, 256, 0, stream>>>(Wih_f, Whh_f, bih_f, bhh_f,
                                         Wih_b, Whh_b, bih_b, bhh_b, ws);
    // L0: gemm chunk 0 only (208 blocks x 4 quarter-tiles = 832 tiles)
    fused_kernel<<<208, 1024, 0, stream>>>(X, mask, ws, 0, 0, 0);
    // L1..L7: rec(c-1) overlapped with gemm(c)
    for (int c = 1; c < NCH; ++c)
        fused_kernel<<<336, 1024, 0, stream>>>(X, mask, ws, c - 1, c, 128);
    // L8: rec chunk 7 only
    fused_kernel<<<128, 1024, 0, stream>>>(X, mask, ws, NCH - 1, 0, 128);
    emis_kernel<<<256, 256, 0, stream>>>(mask, Wl, bl, ws);
    decode_kernel<<<64, 128, 0, stream>>>(mask, labels, trans, start, endv, ws, out);
    fin_kernel<<<1, 64, 0, stream>>>(ws, out);
}